// Round 3
// baseline (233.072 us; speedup 1.0000x reference)
//
#include <hip/hip_runtime.h>
#include <hip/hip_bf16.h>
#include <cstdint>

#define CC 128
#define NN 6400
#define NAa 1600
#define HEADS 4
#define HD 32
#define NB 32
#define MT 64

#define P_ROW 68
#define P_HEAD 1096   // 16*68+8 pad
#define A_ROW 76
#define A_HEAD 1224   // 16*76+8 pad
#define PW (HEADS * P_HEAD)   // 4384 elems per q-subtile
#define AW (HEADS * A_HEAD)   // 4896 elems per q-subtile
// halo buffer: [parity][qs][h][lo][4] bf16
#define HB_IDX(par, qs, hh, lo) (((((par)*2 + (qs))*4 + (hh))*16 + (lo)) * 4)

typedef __attribute__((ext_vector_type(8))) short bfrag8;
typedef __attribute__((ext_vector_type(4))) float ffrag4;
typedef union { uint2 u2[2]; bfrag8 f8; } cvt16;

#define LOG2E 1.4426950408889634f
#define QSCL (0.17677669529663687f * 1.4426950408889634f)

__device__ __forceinline__ float sigmoid_fast(float y) {
  return __builtin_amdgcn_rcpf(1.0f + __builtin_amdgcn_exp2f(-LOG2E * y));
}
__device__ __forceinline__ unsigned short f2bf(float f) {
  unsigned u = __float_as_uint(f);
  return (unsigned short)((u + 0x7FFFu + ((u >> 16) & 1u)) >> 16);
}
__device__ __forceinline__ unsigned pack_bf16(float a, float b) {
  return (unsigned)f2bf(a) | ((unsigned)f2bf(b) << 16);
}
// packed 2xf32 -> 2xbf16 (RNE) — should emit v_cvt_pk_bf16_f32
__device__ __forceinline__ unsigned pk2(float a, float b) {
  float2 f2; f2.x = a; f2.y = b;
  __hip_bfloat162 h = __float22bfloat162_rn(f2);
  union { __hip_bfloat162 h2; unsigned u; } cv; cv.h2 = h;
  return cv.u;
}
__device__ __forceinline__ float bfl(unsigned u) { return __uint_as_float(u << 16); }
__device__ __forceinline__ float bfh(unsigned u) { return __uint_as_float(u & 0xFFFF0000u); }

// ---- K0: prep — x transpose->bf16, weights->bf16 with scales folded ----
__global__ __launch_bounds__(256) void prep_kernel(
    const float* __restrict__ x, const float* __restrict__ w_qk,
    const float* __restrict__ s_qk, const float* __restrict__ w_in,
    const float* __restrict__ s_in, const float* __restrict__ w_out,
    const float* __restrict__ s_out,
    unsigned short* __restrict__ xt, unsigned short* __restrict__ wqkb,
    unsigned short* __restrict__ wob) {
  __shared__ float tile[32][33];
  const int blk = blockIdx.x, tid = threadIdx.x;
  if (blk < 1600) {
    const int b = blk / 800, rem = blk - b * 800;
    const int ct = rem / 200, pt2 = rem - ct * 200;
    const int c0 = ct * 32, px0 = pt2 * 32;
    for (int i = tid; i < 1024; i += 256) {
      int r = i >> 5, p = i & 31;
      tile[r][p] = x[((size_t)(b * CC + c0 + r)) * NN + px0 + p];
    }
    __syncthreads();
    for (int i = tid; i < 512; i += 256) {
      int px = i >> 4, cp = i & 15;
      unsigned pk = pk2(tile[2 * cp][px], tile[2 * cp + 1][px]);
      *(unsigned*)&xt[((size_t)b * NN + px0 + px) * CC + c0 + 2 * cp] = pk;
    }
  } else if (blk < 1608) {
    const int r0 = (blk - 1600) * 48;
    for (int i = tid; i < 6144; i += 256) {
      int r = r0 + (i >> 7), c = i & 127;
      float wv, sv;
      if (r < 2 * CC) { wv = w_qk[r * CC + c]; sv = s_qk[r] * (r < CC ? QSCL : 1.0f); }
      else           { wv = w_in[(r - 2 * CC) * CC + c]; sv = s_in[r - 2 * CC]; }
      wqkb[r * CC + c] = f2bf(wv * sv);
    }
  } else {
    const int r0 = (blk - 1608) * 64;
    for (int i = tid; i < 8192; i += 256) {
      int r = r0 + (i >> 7), c = i & 127;
      wob[r * CC + c] = f2bf(w_out[r * CC + c] * s_out[r]);
    }
  }
}

// ---- K1: qkv as MFMA GEMM (384 x 6400 x K=128), zero LDS ----
__global__ __launch_bounds__(256) void qkv_kernel(
    const unsigned short* __restrict__ xt, const unsigned short* __restrict__ wqkb,
    const float* __restrict__ t_qk, const float* __restrict__ t_in,
    unsigned short* __restrict__ qt, unsigned short* __restrict__ kt,
    unsigned short* __restrict__ vb) {
  const int tid = threadIdx.x;
  const int w = tid >> 6, lane = tid & 63, lo = lane & 15, g = lane >> 4;
  const int blk = blockIdx.x;
  const int b = blk / 400, pt = blk - b * 400;
  const int ng0 = pt * 16;
  const int a = ng0 / NAa, na0 = ng0 - a * NAa;
  const int be = b * 4 + a;
  const size_t xrow = ((size_t)b * NN + ng0 + lo) * CC;
  bfrag8 bf[4];
#pragma unroll
  for (int kk = 0; kk < 4; kk++) bf[kk] = *(const bfrag8*)&xt[xrow + kk * 32 + g * 8];
#pragma unroll
  for (int mt6 = 0; mt6 < 6; mt6++) {
    const int rowbase = (w * 6 + mt6) * 16;
    ffrag4 d = {0.f, 0.f, 0.f, 0.f};
#pragma unroll
    for (int kk = 0; kk < 4; kk++) {
      bfrag8 af = *(const bfrag8*)&wqkb[(size_t)(rowbase + lo) * CC + kk * 32 + g * 8];
      d = __builtin_amdgcn_mfma_f32_16x16x32_bf16(af, bf[kk], d, 0, 0, 0);
    }
    const int r0c = rowbase + 4 * g;
    if (r0c < CC) {
      const int h = r0c >> 5, d0 = r0c & 31;
      uint2 pk;
      pk.x = pk2(d[0] + t_qk[r0c] * QSCL, d[1] + t_qk[r0c + 1] * QSCL);
      pk.y = pk2(d[2] + t_qk[r0c + 2] * QSCL, d[3] + t_qk[r0c + 3] * QSCL);
      *(uint2*)&qt[((size_t)(be * HEADS + h) * NAa + na0 + lo) * HD + d0] = pk;
    } else if (r0c < 2 * CC) {
      const int ch = r0c - CC, h = ch >> 5, d0 = ch & 31;
      uint2 pk;
      pk.x = pk2(d[0] + t_qk[r0c], d[1] + t_qk[r0c + 1]);
      pk.y = pk2(d[2] + t_qk[r0c + 2], d[3] + t_qk[r0c + 3]);
      *(uint2*)&kt[((size_t)(be * HEADS + h) * NAa + na0 + lo) * HD + d0] = pk;
    } else {
      const int ch0 = r0c - 2 * CC;
      const uint2 xv = *(const uint2*)&xt[xrow + ch0];
      float xr[4] = {bfl(xv.x), bfh(xv.x), bfl(xv.y), bfh(xv.y)};
#pragma unroll
      for (int r = 0; r < 4; r++) {
        float y = d[r] + t_in[ch0 + r];
        vb[((size_t)be * CC + ch0 + r) * NAa + na0 + lo] = f2bf(sigmoid_fast(y) * xr[r]);
      }
    }
  }
}

// ---- K2a: partial softmax denominators (M0 = 0, q pre-scaled) ----
__global__ __launch_bounds__(256) void stats_kernel(
    const unsigned short* __restrict__ qt, const unsigned short* __restrict__ kt,
    float* __restrict__ pstats) {
  int tid = threadIdx.x;
  int h = tid >> 6, lane = tid & 63, lo = lane & 15, g = lane >> 4;
  int bid = blockIdx.x;
  int be = bid & 7;
  int rest = bid >> 3;
  int n0 = (rest % 100) * 16;
  int split = rest / 100;
  int ts0 = split ? 12 : 0, ts1 = split ? 25 : 12;

  const unsigned short* qtb = qt + (size_t)(be * HEADS + h) * NAa * HD;
  const unsigned short* ktb = kt + (size_t)(be * HEADS + h) * NAa * HD;

  bfrag8 qf = *(const bfrag8*)(qtb + (size_t)(n0 + lo) * HD + g * 8);
  float sm[4] = {0.f, 0.f, 0.f, 0.f};
  for (int t = ts0; t < ts1; t++) {
    int m0 = t * MT;
#pragma unroll
    for (int sb = 0; sb < 4; sb++) {
      bfrag8 kf = *(const bfrag8*)(ktb + (size_t)(m0 + sb * 16 + lo) * HD + g * 8);
      ffrag4 z = {0.f, 0.f, 0.f, 0.f};
      ffrag4 c = __builtin_amdgcn_mfma_f32_16x16x32_bf16(qf, kf, z, 0, 0, 0);
#pragma unroll
      for (int r = 0; r < 4; r++) sm[r] += __builtin_amdgcn_exp2f(c[r]);
    }
  }
#pragma unroll
  for (int r = 0; r < 4; r++) {
#pragma unroll
    for (int off = 1; off <= 8; off <<= 1) sm[r] += __shfl_xor(sm[r], off);
  }
  if (lo == 0) {
    float4 s4; s4.x = sm[0]; s4.y = sm[1]; s4.z = sm[2]; s4.w = sm[3];
    *(float4*)&pstats[((size_t)(split * 8 + be) * HEADS + h) * NAa + n0 + 4 * g] = s4;
  }
}

// ---- K2b: apply — NB=32 tile, SINGLE-buffered P + parity halo buffer Hb.
//      Schedule per tile: [conv(t): read P,Hb -> write A2] |bar|
//                         [QK(t+1): write P,Hb ; PV(t): read A2] |bar|
//      LDS 39.2 KB -> 4 blocks/CU (32 waves, HW cap); grid 800 <= 1024 slots
//      so every block is resident from t=0 (no dispatch rounds). ----
__global__ __launch_bounds__(512, 8) void apply_kernel(
    const unsigned short* __restrict__ qt, const unsigned short* __restrict__ kt,
    const unsigned short* __restrict__ vb, const float* __restrict__ pstats,
    const float* __restrict__ w_fg, const float* __restrict__ s_fg,
    const float* __restrict__ t_fg, unsigned short* __restrict__ o_part) {
  __shared__ __align__(16) unsigned short Ps[2 * PW];   // 17536 B (cols' 0..63 = keys m0..m0+63)
  __shared__ __align__(16) unsigned short A2s[2 * AW];  // 19584 B
  __shared__ __align__(16) unsigned short Hb[1024];     //  2048 B halo [par][qs][h][lo][4]
  const int tid = threadIdx.x;
  const int w = tid >> 6, lane = tid & 63, lo = lane & 15, g = lane >> 4;
  const int h = w >> 1, u = w & 1;
  const int bid = blockIdx.x;
  const int be = bid & 7;
  const int rest = bid >> 3;
  const int n0 = (rest % 50) * NB;
  const int split = rest / 50;
  const int ts0 = split ? 12 : 0;
  const int tend = split ? 26 : 12;   // t=25 is a virtual tail tile

  const unsigned short* qtb = qt + (size_t)(be * HEADS + h) * NAa * HD;
  const unsigned short* ktb = kt + (size_t)(be * HEADS + h) * NAa * HD;
  const unsigned short* vhb = vb + (size_t)(be * CC + h * HD) * NAa;

  bfrag8 qf[2];
#pragma unroll
  for (int qs = 0; qs < 2; ++qs)
    qf[qs] = *(const bfrag8*)(qtb + (size_t)(n0 + 16 * qs + lo) * HD + g * 8);

  // conv-weight A-fragment (constant): row=lo=(ho*4+s), k=g*8+j
  bfrag8 wfrag;
  {
    const int ho = lo >> 2, s = lo & 3;
#pragma unroll
    for (int j = 0; j < 8; j++) {
      const int tp = j - s;
      float wv = (tp >= 0 && tp < 5) ? w_fg[(ho * HEADS + g) * 5 + tp] : 0.0f;
      wfrag[j] = (short)f2bf(wv);
    }
  }
  const float sfv = s_fg[g], tfv = t_fg[g];

  float inv[2];
#pragma unroll
  for (int qs = 0; qs < 2; ++qs)
    inv[qs] = 1.0f / (pstats[((size_t)(0 + be) * HEADS + h) * NAa + n0 + 16 * qs + lo] +
                      pstats[((size_t)(8 + be) * HEADS + h) * NAa + n0 + 16 * qs + lo]);

  ffrag4 oacc[2][2];
#pragma unroll
  for (int qs = 0; qs < 2; ++qs) {
    ffrag4 z = {0.f, 0.f, 0.f, 0.f};
    oacc[qs][0] = z; oacc[qs][1] = z;
  }

  // ---- prologue: Hb[0] = halo for conv(ts0)  (ts0 is even for both splits) ----
  if (split == 0) {
    if (u == 0 && g == 0) {
      uint2 zz; zz.x = 0; zz.y = 0;
#pragma unroll
      for (int qs = 0; qs < 2; ++qs)
        *(uint2*)&Hb[HB_IDX(0, qs, h, lo)] = zz;
    }
  } else if (u == 0) {
    // halo keys 764..767 from K rows 752..767 (g==3 lanes hold m 764+r)
    bfrag8 kf = *(const bfrag8*)(ktb + (size_t)(752 + lo) * HD + g * 8);
#pragma unroll
    for (int qs = 0; qs < 2; ++qs) {
      ffrag4 z = {0.f, 0.f, 0.f, 0.f};
      ffrag4 c = __builtin_amdgcn_mfma_f32_16x16x32_bf16(kf, qf[qs], z, 0, 0, 0);
      if (g == 3) {
        uint2 pk;
        pk.x = pk2(__builtin_amdgcn_exp2f(c[0]) * inv[qs], __builtin_amdgcn_exp2f(c[1]) * inv[qs]);
        pk.y = pk2(__builtin_amdgcn_exp2f(c[2]) * inv[qs], __builtin_amdgcn_exp2f(c[3]) * inv[qs]);
        *(uint2*)&Hb[HB_IDX(0, qs, h, lo)] = pk;
      }
    }
  }
  // ---- prologue: QK(ts0) -> Ps; sb==3/g==3 lanes also feed Hb[1] (for conv(ts0+1)) ----
  {
    const int m0 = ts0 * MT;
#pragma unroll
    for (int sbi = 0; sbi < 2; sbi++) {
      const int sb = 2 * u + sbi;
      bfrag8 kf = *(const bfrag8*)(ktb + (size_t)(m0 + sb * 16 + lo) * HD + g * 8);
#pragma unroll
      for (int qs = 0; qs < 2; ++qs) {
        ffrag4 z = {0.f, 0.f, 0.f, 0.f};
        ffrag4 c = __builtin_amdgcn_mfma_f32_16x16x32_bf16(kf, qf[qs], z, 0, 0, 0);
        uint2 pk;
        pk.x = pk2(__builtin_amdgcn_exp2f(c[0]) * inv[qs], __builtin_amdgcn_exp2f(c[1]) * inv[qs]);
        pk.y = pk2(__builtin_amdgcn_exp2f(c[2]) * inv[qs], __builtin_amdgcn_exp2f(c[3]) * inv[qs]);
        *(uint2*)&Ps[qs * PW + h * P_HEAD + lo * P_ROW + 16 * sb + 4 * g] = pk;
        if (sb == 3 && g == 3)
          *(uint2*)&Hb[HB_IDX(1, qs, h, lo)] = pk;
      }
    }
  }
  __syncthreads();

  for (int t = ts0; t < tend; t++) {
    const int m0 = t * MT;
    const int par = t & 1;
    // early V loads (k-half u) for PV(t) — shared across q-subtiles
    const bfrag8 vf0 = *(const bfrag8*)(vhb + (size_t)lo * NAa + (m0 - 2 + 32 * u + 8 * g));
    const bfrag8 vf1 = *(const bfrag8*)(vhb + (size_t)(16 + lo) * NAa + (m0 - 2 + 32 * u + 8 * g));
    const bool doqk = (t + 1 < tend);
    const bool realqk = doqk && (t + 1 < 25);
    bfrag8 kf0, kf1;
    if (realqk) {
      const int m1 = (t + 1) * MT;
      kf0 = *(const bfrag8*)(ktb + (size_t)(m1 + (2 * u) * 16 + lo) * HD + g * 8);
      kf1 = *(const bfrag8*)(ktb + (size_t)(m1 + (2 * u + 1) * 16 + lo) * HD + g * 8);
    }
    // ---- phase 1: conv(t) reads Ps (cols' 4i-4..4i+3; i==0 low half from Hb) ----
    const bool edge = (t == 0) || (t == 25);
#pragma unroll
    for (int qs = 0; qs < 2; ++qs) {
#pragma unroll
      for (int ii = 0; ii < 2; ii++) {
        const int i = 2 * w + ii;
        cvt16 bb;
        if (i == 0)
          bb.u2[0] = *(const uint2*)&Hb[HB_IDX(par, qs, g, lo)];
        else
          bb.u2[0] = *(const uint2*)&Ps[qs * PW + g * P_HEAD + lo * P_ROW + 4 * i - 4];
        bb.u2[1] = *(const uint2*)&Ps[qs * PW + g * P_HEAD + lo * P_ROW + 4 * i];
        ffrag4 z = {0.f, 0.f, 0.f, 0.f};
        ffrag4 d = __builtin_amdgcn_mfma_f32_16x16x32_bf16(wfrag, bb.f8, z, 0, 0, 0);
        float a2v[4];
        if (edge) {
#pragma unroll
          for (int r = 0; r < 4; r++) {
            const int mp = m0 - 2 + 4 * i + r;
            float y = d[r] * sfv + tfv;
            float v = y * sigmoid_fast(y);
            a2v[r] = (mp >= 0 && mp < NAa) ? v : 0.0f;
          }
        } else {
#pragma unroll
          for (int r = 0; r < 4; r++) {
            float y = d[r] * sfv + tfv;
            a2v[r] = y * sigmoid_fast(y);
          }
        }
        uint2 pk;
        pk.x = pk2(a2v[0], a2v[1]);
        pk.y = pk2(a2v[2], a2v[3]);
        *(uint2*)&A2s[qs * AW + g * A_HEAD + lo * A_ROW + 4 * i] = pk;
      }
    }
    __syncthreads();
    // ---- phase 2: QK(t+1) -> Ps/Hb, then PV(t) reads A2s ----
    if (doqk) {
      if (realqk) {
#pragma unroll
        for (int qs = 0; qs < 2; ++qs) {
          ffrag4 z = {0.f, 0.f, 0.f, 0.f};
          ffrag4 c0 = __builtin_amdgcn_mfma_f32_16x16x32_bf16(kf0, qf[qs], z, 0, 0, 0);
          ffrag4 c1 = __builtin_amdgcn_mfma_f32_16x16x32_bf16(kf1, qf[qs], z, 0, 0, 0);
          uint2 pk;
          pk.x = pk2(__builtin_amdgcn_exp2f(c0[0]) * inv[qs], __builtin_amdgcn_exp2f(c0[1]) * inv[qs]);
          pk.y = pk2(__builtin_amdgcn_exp2f(c0[2]) * inv[qs], __builtin_amdgcn_exp2f(c0[3]) * inv[qs]);
          *(uint2*)&Ps[qs * PW + h * P_HEAD + lo * P_ROW + 16 * (2 * u) + 4 * g] = pk;
          uint2 pk1;
          pk1.x = pk2(__builtin_amdgcn_exp2f(c1[0]) * inv[qs], __builtin_amdgcn_exp2f(c1[1]) * inv[qs]);
          pk1.y = pk2(__builtin_amdgcn_exp2f(c1[2]) * inv[qs], __builtin_amdgcn_exp2f(c1[3]) * inv[qs]);
          *(uint2*)&Ps[qs * PW + h * P_HEAD + lo * P_ROW + 16 * (2 * u + 1) + 4 * g] = pk1;
          if (u == 1 && g == 3)
            *(uint2*)&Hb[HB_IDX(par, qs, h, lo)] = pk1;   // halo for conv(t+2)
        }
      } else {
        uint2 zz; zz.x = 0; zz.y = 0;
#pragma unroll
        for (int qs = 0; qs < 2; ++qs) {
          *(uint2*)&Ps[qs * PW + h * P_HEAD + lo * P_ROW + 16 * (2 * u) + 4 * g] = zz;
          *(uint2*)&Ps[qs * PW + h * P_HEAD + lo * P_ROW + 16 * (2 * u + 1) + 4 * g] = zz;
        }
      }
    }
    // PV(t): head h, k-half u, both qsubs (V frags shared)
#pragma unroll
    for (int qs = 0; qs < 2; ++qs) {
      cvt16 av;
      av.u2[0] = *(const uint2*)&A2s[qs * AW + h * A_HEAD + lo * A_ROW + 32 * u + 8 * g];
      av.u2[1] = *(const uint2*)&A2s[qs * AW + h * A_HEAD + lo * A_ROW + 32 * u + 8 * g + 4];
      oacc[qs][0] = __builtin_amdgcn_mfma_f32_16x16x32_bf16(av.f8, vf0, oacc[qs][0], 0, 0, 0);
      oacc[qs][1] = __builtin_amdgcn_mfma_f32_16x16x32_bf16(av.f8, vf1, oacc[qs][1], 0, 0, 0);
    }
    __syncthreads();
  }

  // ---- cross-u reduction via A2s scratch, write o_part [split][be][n][c] bf16 ----
  float* scr = (float*)A2s;
  if (u == 1) {
#pragma unroll
    for (int qs = 0; qs < 2; ++qs) {
      float4 f0; f0.x = oacc[qs][0][0]; f0.y = oacc[qs][0][1]; f0.z = oacc[qs][0][2]; f0.w = oacc[qs][0][3];
      float4 f1; f1.x = oacc[qs][1][0]; f1.y = oacc[qs][1][1]; f1.z = oacc[qs][1][2]; f1.w = oacc[qs][1][3];
      *(float4*)&scr[((qs * 4 + h) * 64 + lane) * 8] = f0;
      *(float4*)&scr[((qs * 4 + h) * 64 + lane) * 8 + 4] = f1;
    }
  }
  __syncthreads();
  if (u == 0) {
#pragma unroll
    for (int qs = 0; qs < 2; ++qs) {
      const float4 f0 = *(const float4*)&scr[((qs * 4 + h) * 64 + lane) * 8];
      const float4 f1 = *(const float4*)&scr[((qs * 4 + h) * 64 + lane) * 8 + 4];
      const float fa[4] = {f0.x, f0.y, f0.z, f0.w};
      const float fb[4] = {f1.x, f1.y, f1.z, f1.w};
#pragma unroll
      for (int r = 0; r < 4; r++) {
        const size_t rowoff = ((size_t)(split * 8 + be) * NAa + n0 + 16 * qs + 4 * g + r) * CC;
        o_part[rowoff + h * HD + lo] = f2bf(oacc[qs][0][r] + fa[r]);
        o_part[rowoff + h * HD + 16 + lo] = f2bf(oacc[qs][1][r] + fb[r]);
      }
    }
  }
}

// ---- K3: out as MFMA GEMM + SiLU-gate + residual ----
__global__ __launch_bounds__(256) void out_kernel(
    const unsigned short* __restrict__ o_part, const unsigned short* __restrict__ wob,
    const float* __restrict__ t_out, const float* __restrict__ x,
    float* __restrict__ out) {
  const int tid = threadIdx.x;
  const int w = tid >> 6, lane = tid & 63, lo = lane & 15, g = lane >> 4;
  const int blk = blockIdx.x;
  const int b = blk / 400, pt = blk - b * 400;
  const int ng0 = pt * 16;
  const int a = ng0 / NAa, na0 = ng0 - a * NAa;
  const int be = b * 4 + a;
  const size_t orow0 = ((size_t)(0 * 8 + be) * NAa + na0 + lo) * CC;
  const size_t orow1 = ((size_t)(1 * 8 + be) * NAa + na0 + lo) * CC;
  bfrag8 bf0[4], bf1[4];
#pragma unroll
  for (int kk = 0; kk < 4; kk++) {
    bf0[kk] = *(const bfrag8*)&o_part[orow0 + kk * 32 + g * 8];
    bf1[kk] = *(const bfrag8*)&o_part[orow1 + kk * 32 + g * 8];
  }
#pragma unroll
  for (int mt2 = 0; mt2 < 2; mt2++) {
    const int rowbase = (w * 2 + mt2) * 16;
    ffrag4 d = {0.f, 0.f, 0.f, 0.f};
#pragma unroll
    for (int kk = 0; kk < 4; kk++) {
      bfrag8 af = *(const bfrag8*)&wob[(size_t)(rowbase + lo) * CC + kk * 32 + g * 8];
      d = __builtin_amdgcn_mfma_f32_16x16x32_bf16(af, bf0[kk], d, 0, 0, 0);
      d = __builtin_amdgcn_mfma_f32_16x16x32_bf16(af, bf1[kk], d, 0, 0, 0);
    }
    const int ch0 = rowbase + 4 * g;
    const uint2 q0 = *(const uint2*)&o_part[orow0 + ch0];
    const uint2 q1 = *(const uint2*)&o_part[orow1 + ch0];
    float ov[4] = {bfl(q0.x) + bfl(q1.x), bfh(q0.x) + bfh(q1.x),
                   bfl(q0.y) + bfl(q1.y), bfh(q0.y) + bfh(q1.y)};
#pragma unroll
    for (int r = 0; r < 4; r++) {
      const size_t xi = ((size_t)b * CC + ch0 + r) * NN + ng0 + lo;
      float y = d[r] + t_out[ch0 + r];
      out[xi] = ov[r] * sigmoid_fast(y) + x[xi];
    }
  }
}

extern "C" void kernel_launch(void* const* d_in, const int* in_sizes, int n_in,
                              void* d_out, int out_size, void* d_ws, size_t ws_size,
                              hipStream_t stream) {
  const float* x    = (const float*)d_in[0];
  const float* w_qk = (const float*)d_in[1];
  const float* s_qk = (const float*)d_in[2];
  const float* t_qk = (const float*)d_in[3];
  const float* w_in = (const float*)d_in[4];
  const float* s_in = (const float*)d_in[5];
  const float* t_in = (const float*)d_in[6];
  const float* w_out = (const float*)d_in[7];
  const float* s_out = (const float*)d_in[8];
  const float* t_out = (const float*)d_in[9];
  const float* w_fg = (const float*)d_in[10];
  const float* s_fg = (const float*)d_in[11];
  const float* t_fg = (const float*)d_in[12];

  char* wsb = (char*)d_ws;
  unsigned short* o_part = (unsigned short*)wsb;               // 6,553,600 B  [split][be][n][c] bf16
  unsigned short* vb_raw = (unsigned short*)(wsb + 6553600);   // 3,276,864 B
  unsigned short* vbp = vb_raw + 2;
  unsigned short* qt = (unsigned short*)(wsb + 9830464);       // 3,276,800 B
  unsigned short* kt = (unsigned short*)(wsb + 13107264);      // 3,276,800 B
  unsigned short* xt = (unsigned short*)(wsb + 16384064);      // 3,276,800 B
  unsigned short* wqkb = (unsigned short*)(wsb + 19660864);    //    98,304 B
  unsigned short* wob = (unsigned short*)(wsb + 19759168);     //    32,768 B
  float* pstats = (float*)(wsb + 19791936);                    // 1,638,400 B
  float* out = (float*)d_out;

  prep_kernel<<<1610, 256, 0, stream>>>(x, w_qk, s_qk, w_in, s_in, w_out, s_out, xt, wqkb, wob);
  qkv_kernel<<<800, 256, 0, stream>>>(xt, wqkb, t_qk, t_in, qt, kt, vbp);
  stats_kernel<<<1600, 256, 0, stream>>>(qt, kt, pstats);
  apply_kernel<<<800, 512, 0, stream>>>(qt, kt, vbp, pstats, w_fg, s_fg, t_fg, o_part);
  out_kernel<<<800, 256, 0, stream>>>(o_part, wob, t_out, x, out);
}

// Round 4
// 134.636 us; speedup vs baseline: 1.7311x; 1.7311x over previous
//
#include <hip/hip_runtime.h>
#include <hip/hip_bf16.h>
#include <cstdint>

#define CC 128
#define NN 6400
#define NAa 1600
#define HEADS 4
#define HD 32
#define NB 32
#define MT 64

#define P_ROW 68
#define P_HEAD 1096   // 16*68+8 pad
#define A_ROW 76
#define A_HEAD 1224   // 16*76+8 pad
#define PW (HEADS * P_HEAD)   // 4384 elems per q-subtile
#define AW (HEADS * A_HEAD)   // 4896 elems per q-subtile
// halo buffer: [parity][qs][h][lo][4] bf16
#define HB_IDX(par, qs, hh, lo) (((((par)*2 + (qs))*4 + (hh))*16 + (lo)) * 4)

typedef __attribute__((ext_vector_type(8))) short bfrag8;
typedef __attribute__((ext_vector_type(4))) float ffrag4;
typedef union { uint2 u2[2]; bfrag8 f8; } cvt16;

#define LOG2E 1.4426950408889634f
#define QSCL (0.17677669529663687f * 1.4426950408889634f)

__device__ __forceinline__ float sigmoid_fast(float y) {
  return __builtin_amdgcn_rcpf(1.0f + __builtin_amdgcn_exp2f(-LOG2E * y));
}
__device__ __forceinline__ unsigned short f2bf(float f) {
  unsigned u = __float_as_uint(f);
  return (unsigned short)((u + 0x7FFFu + ((u >> 16) & 1u)) >> 16);
}
__device__ __forceinline__ unsigned pack_bf16(float a, float b) {
  return (unsigned)f2bf(a) | ((unsigned)f2bf(b) << 16);
}
// packed 2xf32 -> 2xbf16 (RNE) — should emit v_cvt_pk_bf16_f32
__device__ __forceinline__ unsigned pk2(float a, float b) {
  float2 f2; f2.x = a; f2.y = b;
  __hip_bfloat162 h = __float22bfloat162_rn(f2);
  union { __hip_bfloat162 h2; unsigned u; } cv; cv.h2 = h;
  return cv.u;
}
__device__ __forceinline__ float bfl(unsigned u) { return __uint_as_float(u << 16); }
__device__ __forceinline__ float bfh(unsigned u) { return __uint_as_float(u & 0xFFFF0000u); }

// ---- K0: prep — x transpose->bf16, weights->bf16 with scales folded ----
__global__ __launch_bounds__(256) void prep_kernel(
    const float* __restrict__ x, const float* __restrict__ w_qk,
    const float* __restrict__ s_qk, const float* __restrict__ w_in,
    const float* __restrict__ s_in, const float* __restrict__ w_out,
    const float* __restrict__ s_out,
    unsigned short* __restrict__ xt, unsigned short* __restrict__ wqkb,
    unsigned short* __restrict__ wob) {
  __shared__ float tile[32][33];
  const int blk = blockIdx.x, tid = threadIdx.x;
  if (blk < 1600) {
    const int b = blk / 800, rem = blk - b * 800;
    const int ct = rem / 200, pt2 = rem - ct * 200;
    const int c0 = ct * 32, px0 = pt2 * 32;
    for (int i = tid; i < 1024; i += 256) {
      int r = i >> 5, p = i & 31;
      tile[r][p] = x[((size_t)(b * CC + c0 + r)) * NN + px0 + p];
    }
    __syncthreads();
    for (int i = tid; i < 512; i += 256) {
      int px = i >> 4, cp = i & 15;
      unsigned pk = pk2(tile[2 * cp][px], tile[2 * cp + 1][px]);
      *(unsigned*)&xt[((size_t)b * NN + px0 + px) * CC + c0 + 2 * cp] = pk;
    }
  } else if (blk < 1608) {
    const int r0 = (blk - 1600) * 48;
    for (int i = tid; i < 6144; i += 256) {
      int r = r0 + (i >> 7), c = i & 127;
      float wv, sv;
      if (r < 2 * CC) { wv = w_qk[r * CC + c]; sv = s_qk[r] * (r < CC ? QSCL : 1.0f); }
      else           { wv = w_in[(r - 2 * CC) * CC + c]; sv = s_in[r - 2 * CC]; }
      wqkb[r * CC + c] = f2bf(wv * sv);
    }
  } else {
    const int r0 = (blk - 1608) * 64;
    for (int i = tid; i < 8192; i += 256) {
      int r = r0 + (i >> 7), c = i & 127;
      wob[r * CC + c] = f2bf(w_out[r * CC + c] * s_out[r]);
    }
  }
}

// ---- K1: qkv as MFMA GEMM (384 x 6400 x K=128), zero LDS ----
__global__ __launch_bounds__(256) void qkv_kernel(
    const unsigned short* __restrict__ xt, const unsigned short* __restrict__ wqkb,
    const float* __restrict__ t_qk, const float* __restrict__ t_in,
    unsigned short* __restrict__ qt, unsigned short* __restrict__ kt,
    unsigned short* __restrict__ vb) {
  const int tid = threadIdx.x;
  const int w = tid >> 6, lane = tid & 63, lo = lane & 15, g = lane >> 4;
  const int blk = blockIdx.x;
  const int b = blk / 400, pt = blk - b * 400;
  const int ng0 = pt * 16;
  const int a = ng0 / NAa, na0 = ng0 - a * NAa;
  const int be = b * 4 + a;
  const size_t xrow = ((size_t)b * NN + ng0 + lo) * CC;
  bfrag8 bf[4];
#pragma unroll
  for (int kk = 0; kk < 4; kk++) bf[kk] = *(const bfrag8*)&xt[xrow + kk * 32 + g * 8];
#pragma unroll
  for (int mt6 = 0; mt6 < 6; mt6++) {
    const int rowbase = (w * 6 + mt6) * 16;
    ffrag4 d = {0.f, 0.f, 0.f, 0.f};
#pragma unroll
    for (int kk = 0; kk < 4; kk++) {
      bfrag8 af = *(const bfrag8*)&wqkb[(size_t)(rowbase + lo) * CC + kk * 32 + g * 8];
      d = __builtin_amdgcn_mfma_f32_16x16x32_bf16(af, bf[kk], d, 0, 0, 0);
    }
    const int r0c = rowbase + 4 * g;
    if (r0c < CC) {
      const int h = r0c >> 5, d0 = r0c & 31;
      uint2 pk;
      pk.x = pk2(d[0] + t_qk[r0c] * QSCL, d[1] + t_qk[r0c + 1] * QSCL);
      pk.y = pk2(d[2] + t_qk[r0c + 2] * QSCL, d[3] + t_qk[r0c + 3] * QSCL);
      *(uint2*)&qt[((size_t)(be * HEADS + h) * NAa + na0 + lo) * HD + d0] = pk;
    } else if (r0c < 2 * CC) {
      const int ch = r0c - CC, h = ch >> 5, d0 = ch & 31;
      uint2 pk;
      pk.x = pk2(d[0] + t_qk[r0c], d[1] + t_qk[r0c + 1]);
      pk.y = pk2(d[2] + t_qk[r0c + 2], d[3] + t_qk[r0c + 3]);
      *(uint2*)&kt[((size_t)(be * HEADS + h) * NAa + na0 + lo) * HD + d0] = pk;
    } else {
      const int ch0 = r0c - 2 * CC;
      const uint2 xv = *(const uint2*)&xt[xrow + ch0];
      float xr[4] = {bfl(xv.x), bfh(xv.x), bfl(xv.y), bfh(xv.y)};
#pragma unroll
      for (int r = 0; r < 4; r++) {
        float y = d[r] + t_in[ch0 + r];
        vb[((size_t)be * CC + ch0 + r) * NAa + na0 + lo] = f2bf(sigmoid_fast(y) * xr[r]);
      }
    }
  }
}

// ---- K2a: partial softmax denominators (M0 = 0, q pre-scaled) ----
__global__ __launch_bounds__(256) void stats_kernel(
    const unsigned short* __restrict__ qt, const unsigned short* __restrict__ kt,
    float* __restrict__ pstats) {
  int tid = threadIdx.x;
  int h = tid >> 6, lane = tid & 63, lo = lane & 15, g = lane >> 4;
  int bid = blockIdx.x;
  int be = bid & 7;
  int rest = bid >> 3;
  int n0 = (rest % 100) * 16;
  int split = rest / 100;
  int ts0 = split ? 12 : 0, ts1 = split ? 25 : 12;

  const unsigned short* qtb = qt + (size_t)(be * HEADS + h) * NAa * HD;
  const unsigned short* ktb = kt + (size_t)(be * HEADS + h) * NAa * HD;

  bfrag8 qf = *(const bfrag8*)(qtb + (size_t)(n0 + lo) * HD + g * 8);
  float sm[4] = {0.f, 0.f, 0.f, 0.f};
  for (int t = ts0; t < ts1; t++) {
    int m0 = t * MT;
#pragma unroll
    for (int sb = 0; sb < 4; sb++) {
      bfrag8 kf = *(const bfrag8*)(ktb + (size_t)(m0 + sb * 16 + lo) * HD + g * 8);
      ffrag4 z = {0.f, 0.f, 0.f, 0.f};
      ffrag4 c = __builtin_amdgcn_mfma_f32_16x16x32_bf16(qf, kf, z, 0, 0, 0);
#pragma unroll
      for (int r = 0; r < 4; r++) sm[r] += __builtin_amdgcn_exp2f(c[r]);
    }
  }
#pragma unroll
  for (int r = 0; r < 4; r++) {
#pragma unroll
    for (int off = 1; off <= 8; off <<= 1) sm[r] += __shfl_xor(sm[r], off);
  }
  if (lo == 0) {
    float4 s4; s4.x = sm[0]; s4.y = sm[1]; s4.z = sm[2]; s4.w = sm[3];
    *(float4*)&pstats[((size_t)(split * 8 + be) * HEADS + h) * NAa + n0 + 4 * g] = s4;
  }
}

// ---- K2b: apply — NB=32 tile, SINGLE-buffered P + parity halo buffer Hb.
//      Schedule per tile: [conv(t): read P,Hb -> write A2] |bar|
//                         [QK(t+1): write P,Hb ; PV(t): read A2] |bar|
//      LDS 39.2 KB allows 4 blocks/CU; NO min-waves hint (R3's ",8" forced a
//      64-reg budget -> catastrophic scratch spill, 380 MB HBM traffic). ----
__global__ __launch_bounds__(512) void apply_kernel(
    const unsigned short* __restrict__ qt, const unsigned short* __restrict__ kt,
    const unsigned short* __restrict__ vb, const float* __restrict__ pstats,
    const float* __restrict__ w_fg, const float* __restrict__ s_fg,
    const float* __restrict__ t_fg, unsigned short* __restrict__ o_part) {
  __shared__ __align__(16) unsigned short Ps[2 * PW];   // 17536 B (cols' 0..63 = keys m0..m0+63)
  __shared__ __align__(16) unsigned short A2s[2 * AW];  // 19584 B
  __shared__ __align__(16) unsigned short Hb[1024];     //  2048 B halo [par][qs][h][lo][4]
  const int tid = threadIdx.x;
  const int w = tid >> 6, lane = tid & 63, lo = lane & 15, g = lane >> 4;
  const int h = w >> 1, u = w & 1;
  const int bid = blockIdx.x;
  const int be = bid & 7;
  const int rest = bid >> 3;
  const int n0 = (rest % 50) * NB;
  const int split = rest / 50;
  const int ts0 = split ? 12 : 0;
  const int tend = split ? 26 : 12;   // t=25 is a virtual tail tile

  const unsigned short* qtb = qt + (size_t)(be * HEADS + h) * NAa * HD;
  const unsigned short* ktb = kt + (size_t)(be * HEADS + h) * NAa * HD;
  const unsigned short* vhb = vb + (size_t)(be * CC + h * HD) * NAa;

  bfrag8 qf[2];
#pragma unroll
  for (int qs = 0; qs < 2; ++qs)
    qf[qs] = *(const bfrag8*)(qtb + (size_t)(n0 + 16 * qs + lo) * HD + g * 8);

  // conv-weight A-fragment (constant): row=lo=(ho*4+s), k=g*8+j
  bfrag8 wfrag;
  {
    const int ho = lo >> 2, s = lo & 3;
#pragma unroll
    for (int j = 0; j < 8; j++) {
      const int tp = j - s;
      float wv = (tp >= 0 && tp < 5) ? w_fg[(ho * HEADS + g) * 5 + tp] : 0.0f;
      wfrag[j] = (short)f2bf(wv);
    }
  }
  const float sfv = s_fg[g], tfv = t_fg[g];

  float inv[2];
#pragma unroll
  for (int qs = 0; qs < 2; ++qs)
    inv[qs] = 1.0f / (pstats[((size_t)(0 + be) * HEADS + h) * NAa + n0 + 16 * qs + lo] +
                      pstats[((size_t)(8 + be) * HEADS + h) * NAa + n0 + 16 * qs + lo]);

  ffrag4 oacc[2][2];
#pragma unroll
  for (int qs = 0; qs < 2; ++qs) {
    ffrag4 z = {0.f, 0.f, 0.f, 0.f};
    oacc[qs][0] = z; oacc[qs][1] = z;
  }

  // ---- prologue: Hb[0] = halo for conv(ts0)  (ts0 is even for both splits) ----
  if (split == 0) {
    if (u == 0 && g == 0) {
      uint2 zz; zz.x = 0; zz.y = 0;
#pragma unroll
      for (int qs = 0; qs < 2; ++qs)
        *(uint2*)&Hb[HB_IDX(0, qs, h, lo)] = zz;
    }
  } else if (u == 0) {
    // halo keys 764..767 from K rows 752..767 (g==3 lanes hold m 764+r)
    bfrag8 kf = *(const bfrag8*)(ktb + (size_t)(752 + lo) * HD + g * 8);
#pragma unroll
    for (int qs = 0; qs < 2; ++qs) {
      ffrag4 z = {0.f, 0.f, 0.f, 0.f};
      ffrag4 c = __builtin_amdgcn_mfma_f32_16x16x32_bf16(kf, qf[qs], z, 0, 0, 0);
      if (g == 3) {
        uint2 pk;
        pk.x = pk2(__builtin_amdgcn_exp2f(c[0]) * inv[qs], __builtin_amdgcn_exp2f(c[1]) * inv[qs]);
        pk.y = pk2(__builtin_amdgcn_exp2f(c[2]) * inv[qs], __builtin_amdgcn_exp2f(c[3]) * inv[qs]);
        *(uint2*)&Hb[HB_IDX(0, qs, h, lo)] = pk;
      }
    }
  }
  // ---- prologue: QK(ts0) -> Ps; sb==3/g==3 lanes also feed Hb[1] (for conv(ts0+1)) ----
  {
    const int m0 = ts0 * MT;
#pragma unroll
    for (int sbi = 0; sbi < 2; sbi++) {
      const int sb = 2 * u + sbi;
      bfrag8 kf = *(const bfrag8*)(ktb + (size_t)(m0 + sb * 16 + lo) * HD + g * 8);
#pragma unroll
      for (int qs = 0; qs < 2; ++qs) {
        ffrag4 z = {0.f, 0.f, 0.f, 0.f};
        ffrag4 c = __builtin_amdgcn_mfma_f32_16x16x32_bf16(kf, qf[qs], z, 0, 0, 0);
        uint2 pk;
        pk.x = pk2(__builtin_amdgcn_exp2f(c[0]) * inv[qs], __builtin_amdgcn_exp2f(c[1]) * inv[qs]);
        pk.y = pk2(__builtin_amdgcn_exp2f(c[2]) * inv[qs], __builtin_amdgcn_exp2f(c[3]) * inv[qs]);
        *(uint2*)&Ps[qs * PW + h * P_HEAD + lo * P_ROW + 16 * sb + 4 * g] = pk;
        if (sb == 3 && g == 3)
          *(uint2*)&Hb[HB_IDX(1, qs, h, lo)] = pk;
      }
    }
  }
  __syncthreads();

  for (int t = ts0; t < tend; t++) {
    const int m0 = t * MT;
    const int par = t & 1;
    // early V loads (k-half u) for PV(t) — shared across q-subtiles
    const bfrag8 vf0 = *(const bfrag8*)(vhb + (size_t)lo * NAa + (m0 - 2 + 32 * u + 8 * g));
    const bfrag8 vf1 = *(const bfrag8*)(vhb + (size_t)(16 + lo) * NAa + (m0 - 2 + 32 * u + 8 * g));
    const bool doqk = (t + 1 < tend);
    const bool realqk = doqk && (t + 1 < 25);
    bfrag8 kf0, kf1;
    if (realqk) {
      const int m1 = (t + 1) * MT;
      kf0 = *(const bfrag8*)(ktb + (size_t)(m1 + (2 * u) * 16 + lo) * HD + g * 8);
      kf1 = *(const bfrag8*)(ktb + (size_t)(m1 + (2 * u + 1) * 16 + lo) * HD + g * 8);
    }
    // ---- phase 1: conv(t) reads Ps (cols' 4i-4..4i+3; i==0 low half from Hb) ----
    const bool edge = (t == 0) || (t == 25);
#pragma unroll
    for (int qs = 0; qs < 2; ++qs) {
#pragma unroll
      for (int ii = 0; ii < 2; ii++) {
        const int i = 2 * w + ii;
        cvt16 bb;
        if (i == 0)
          bb.u2[0] = *(const uint2*)&Hb[HB_IDX(par, qs, g, lo)];
        else
          bb.u2[0] = *(const uint2*)&Ps[qs * PW + g * P_HEAD + lo * P_ROW + 4 * i - 4];
        bb.u2[1] = *(const uint2*)&Ps[qs * PW + g * P_HEAD + lo * P_ROW + 4 * i];
        ffrag4 z = {0.f, 0.f, 0.f, 0.f};
        ffrag4 d = __builtin_amdgcn_mfma_f32_16x16x32_bf16(wfrag, bb.f8, z, 0, 0, 0);
        float a2v[4];
        if (edge) {
#pragma unroll
          for (int r = 0; r < 4; r++) {
            const int mp = m0 - 2 + 4 * i + r;
            float y = d[r] * sfv + tfv;
            float v = y * sigmoid_fast(y);
            a2v[r] = (mp >= 0 && mp < NAa) ? v : 0.0f;
          }
        } else {
#pragma unroll
          for (int r = 0; r < 4; r++) {
            float y = d[r] * sfv + tfv;
            a2v[r] = y * sigmoid_fast(y);
          }
        }
        uint2 pk;
        pk.x = pk2(a2v[0], a2v[1]);
        pk.y = pk2(a2v[2], a2v[3]);
        *(uint2*)&A2s[qs * AW + g * A_HEAD + lo * A_ROW + 4 * i] = pk;
      }
    }
    __syncthreads();
    // ---- phase 2: QK(t+1) -> Ps/Hb, then PV(t) reads A2s ----
    if (doqk) {
      if (realqk) {
#pragma unroll
        for (int qs = 0; qs < 2; ++qs) {
          ffrag4 z = {0.f, 0.f, 0.f, 0.f};
          ffrag4 c0 = __builtin_amdgcn_mfma_f32_16x16x32_bf16(kf0, qf[qs], z, 0, 0, 0);
          ffrag4 c1 = __builtin_amdgcn_mfma_f32_16x16x32_bf16(kf1, qf[qs], z, 0, 0, 0);
          uint2 pk;
          pk.x = pk2(__builtin_amdgcn_exp2f(c0[0]) * inv[qs], __builtin_amdgcn_exp2f(c0[1]) * inv[qs]);
          pk.y = pk2(__builtin_amdgcn_exp2f(c0[2]) * inv[qs], __builtin_amdgcn_exp2f(c0[3]) * inv[qs]);
          *(uint2*)&Ps[qs * PW + h * P_HEAD + lo * P_ROW + 16 * (2 * u) + 4 * g] = pk;
          uint2 pk1;
          pk1.x = pk2(__builtin_amdgcn_exp2f(c1[0]) * inv[qs], __builtin_amdgcn_exp2f(c1[1]) * inv[qs]);
          pk1.y = pk2(__builtin_amdgcn_exp2f(c1[2]) * inv[qs], __builtin_amdgcn_exp2f(c1[3]) * inv[qs]);
          *(uint2*)&Ps[qs * PW + h * P_HEAD + lo * P_ROW + 16 * (2 * u + 1) + 4 * g] = pk1;
          if (u == 1 && g == 3)
            *(uint2*)&Hb[HB_IDX(par, qs, h, lo)] = pk1;   // halo for conv(t+2)
        }
      } else {
        uint2 zz; zz.x = 0; zz.y = 0;
#pragma unroll
        for (int qs = 0; qs < 2; ++qs) {
          *(uint2*)&Ps[qs * PW + h * P_HEAD + lo * P_ROW + 16 * (2 * u) + 4 * g] = zz;
          *(uint2*)&Ps[qs * PW + h * P_HEAD + lo * P_ROW + 16 * (2 * u + 1) + 4 * g] = zz;
        }
      }
    }
    // PV(t): head h, k-half u, both qsubs (V frags shared)
#pragma unroll
    for (int qs = 0; qs < 2; ++qs) {
      cvt16 av;
      av.u2[0] = *(const uint2*)&A2s[qs * AW + h * A_HEAD + lo * A_ROW + 32 * u + 8 * g];
      av.u2[1] = *(const uint2*)&A2s[qs * AW + h * A_HEAD + lo * A_ROW + 32 * u + 8 * g + 4];
      oacc[qs][0] = __builtin_amdgcn_mfma_f32_16x16x32_bf16(av.f8, vf0, oacc[qs][0], 0, 0, 0);
      oacc[qs][1] = __builtin_amdgcn_mfma_f32_16x16x32_bf16(av.f8, vf1, oacc[qs][1], 0, 0, 0);
    }
    __syncthreads();
  }

  // ---- cross-u reduction via A2s scratch, write o_part [split][be][n][c] bf16 ----
  float* scr = (float*)A2s;
  if (u == 1) {
#pragma unroll
    for (int qs = 0; qs < 2; ++qs) {
      float4 f0; f0.x = oacc[qs][0][0]; f0.y = oacc[qs][0][1]; f0.z = oacc[qs][0][2]; f0.w = oacc[qs][0][3];
      float4 f1; f1.x = oacc[qs][1][0]; f1.y = oacc[qs][1][1]; f1.z = oacc[qs][1][2]; f1.w = oacc[qs][1][3];
      *(float4*)&scr[((qs * 4 + h) * 64 + lane) * 8] = f0;
      *(float4*)&scr[((qs * 4 + h) * 64 + lane) * 8 + 4] = f1;
    }
  }
  __syncthreads();
  if (u == 0) {
#pragma unroll
    for (int qs = 0; qs < 2; ++qs) {
      const float4 f0 = *(const float4*)&scr[((qs * 4 + h) * 64 + lane) * 8];
      const float4 f1 = *(const float4*)&scr[((qs * 4 + h) * 64 + lane) * 8 + 4];
      const float fa[4] = {f0.x, f0.y, f0.z, f0.w};
      const float fb[4] = {f1.x, f1.y, f1.z, f1.w};
#pragma unroll
      for (int r = 0; r < 4; r++) {
        const size_t rowoff = ((size_t)(split * 8 + be) * NAa + n0 + 16 * qs + 4 * g + r) * CC;
        o_part[rowoff + h * HD + lo] = f2bf(oacc[qs][0][r] + fa[r]);
        o_part[rowoff + h * HD + 16 + lo] = f2bf(oacc[qs][1][r] + fb[r]);
      }
    }
  }
}

// ---- K3: out as MFMA GEMM + SiLU-gate + residual ----
__global__ __launch_bounds__(256) void out_kernel(
    const unsigned short* __restrict__ o_part, const unsigned short* __restrict__ wob,
    const float* __restrict__ t_out, const float* __restrict__ x,
    float* __restrict__ out) {
  const int tid = threadIdx.x;
  const int w = tid >> 6, lane = tid & 63, lo = lane & 15, g = lane >> 4;
  const int blk = blockIdx.x;
  const int b = blk / 400, pt = blk - b * 400;
  const int ng0 = pt * 16;
  const int a = ng0 / NAa, na0 = ng0 - a * NAa;
  const int be = b * 4 + a;
  const size_t orow0 = ((size_t)(0 * 8 + be) * NAa + na0 + lo) * CC;
  const size_t orow1 = ((size_t)(1 * 8 + be) * NAa + na0 + lo) * CC;
  bfrag8 bf0[4], bf1[4];
#pragma unroll
  for (int kk = 0; kk < 4; kk++) {
    bf0[kk] = *(const bfrag8*)&o_part[orow0 + kk * 32 + g * 8];
    bf1[kk] = *(const bfrag8*)&o_part[orow1 + kk * 32 + g * 8];
  }
#pragma unroll
  for (int mt2 = 0; mt2 < 2; mt2++) {
    const int rowbase = (w * 2 + mt2) * 16;
    ffrag4 d = {0.f, 0.f, 0.f, 0.f};
#pragma unroll
    for (int kk = 0; kk < 4; kk++) {
      bfrag8 af = *(const bfrag8*)&wob[(size_t)(rowbase + lo) * CC + kk * 32 + g * 8];
      d = __builtin_amdgcn_mfma_f32_16x16x32_bf16(af, bf0[kk], d, 0, 0, 0);
      d = __builtin_amdgcn_mfma_f32_16x16x32_bf16(af, bf1[kk], d, 0, 0, 0);
    }
    const int ch0 = rowbase + 4 * g;
    const uint2 q0 = *(const uint2*)&o_part[orow0 + ch0];
    const uint2 q1 = *(const uint2*)&o_part[orow1 + ch0];
    float ov[4] = {bfl(q0.x) + bfl(q1.x), bfh(q0.x) + bfh(q1.x),
                   bfl(q0.y) + bfl(q1.y), bfh(q0.y) + bfh(q1.y)};
#pragma unroll
    for (int r = 0; r < 4; r++) {
      const size_t xi = ((size_t)b * CC + ch0 + r) * NN + ng0 + lo;
      float y = d[r] + t_out[ch0 + r];
      out[xi] = ov[r] * sigmoid_fast(y) + x[xi];
    }
  }
}

extern "C" void kernel_launch(void* const* d_in, const int* in_sizes, int n_in,
                              void* d_out, int out_size, void* d_ws, size_t ws_size,
                              hipStream_t stream) {
  const float* x    = (const float*)d_in[0];
  const float* w_qk = (const float*)d_in[1];
  const float* s_qk = (const float*)d_in[2];
  const float* t_qk = (const float*)d_in[3];
  const float* w_in = (const float*)d_in[4];
  const float* s_in = (const float*)d_in[5];
  const float* t_in = (const float*)d_in[6];
  const float* w_out = (const float*)d_in[7];
  const float* s_out = (const float*)d_in[8];
  const float* t_out = (const float*)d_in[9];
  const float* w_fg = (const float*)d_in[10];
  const float* s_fg = (const float*)d_in[11];
  const float* t_fg = (const float*)d_in[12];

  char* wsb = (char*)d_ws;
  unsigned short* o_part = (unsigned short*)wsb;               // 6,553,600 B  [split][be][n][c] bf16
  unsigned short* vb_raw = (unsigned short*)(wsb + 6553600);   // 3,276,864 B
  unsigned short* vbp = vb_raw + 2;
  unsigned short* qt = (unsigned short*)(wsb + 9830464);       // 3,276,800 B
  unsigned short* kt = (unsigned short*)(wsb + 13107264);      // 3,276,800 B
  unsigned short* xt = (unsigned short*)(wsb + 16384064);      // 3,276,800 B
  unsigned short* wqkb = (unsigned short*)(wsb + 19660864);    //    98,304 B
  unsigned short* wob = (unsigned short*)(wsb + 19759168);     //    32,768 B
  float* pstats = (float*)(wsb + 19791936);                    // 1,638,400 B
  float* out = (float*)d_out;

  prep_kernel<<<1610, 256, 0, stream>>>(x, w_qk, s_qk, w_in, s_in, w_out, s_out, xt, wqkb, wob);
  qkv_kernel<<<800, 256, 0, stream>>>(xt, wqkb, t_qk, t_in, qt, kt, vbp);
  stats_kernel<<<1600, 256, 0, stream>>>(qt, kt, pstats);
  apply_kernel<<<800, 512, 0, stream>>>(qt, kt, vbp, pstats, w_fg, s_fg, t_fg, o_part);
  out_kernel<<<800, 256, 0, stream>>>(o_part, wob, t_out, x, out);
}

// Round 5
// 129.833 us; speedup vs baseline: 1.7952x; 1.0370x over previous
//
#include <hip/hip_runtime.h>
#include <hip/hip_bf16.h>
#include <cstdint>

#define CC 128
#define NN 6400
#define NAa 1600
#define HEADS 4
#define HD 32
#define NB 32
#define MT 64

#define P_ROW 68
#define P_HEAD 1096   // 16*68+8 pad
#define A_ROW 76
#define A_HEAD 1224   // 16*76+8 pad
#define PW (HEADS * P_HEAD)   // 4384 elems per q-subtile
#define AW (HEADS * A_HEAD)   // 4896 elems per q-subtile
// halo buffer: [parity][qs][h][lo][4] bf16
#define HB_IDX(par, qs, hh, lo) (((((par)*2 + (qs))*4 + (hh))*16 + (lo)) * 4)
#define XROW 136              // qkv LDS x-tile row stride (16B-aligned: 272 B)

typedef __attribute__((ext_vector_type(8))) short bfrag8;
typedef __attribute__((ext_vector_type(4))) float ffrag4;
typedef union { uint2 u2[2]; bfrag8 f8; } cvt16;

#define LOG2E 1.4426950408889634f
#define QSCL (0.17677669529663687f * 1.4426950408889634f)

__device__ __forceinline__ float sigmoid_fast(float y) {
  return __builtin_amdgcn_rcpf(1.0f + __builtin_amdgcn_exp2f(-LOG2E * y));
}
__device__ __forceinline__ unsigned short f2bf(float f) {
  unsigned u = __float_as_uint(f);
  return (unsigned short)((u + 0x7FFFu + ((u >> 16) & 1u)) >> 16);
}
// packed 2xf32 -> 2xbf16 (RNE) — should emit v_cvt_pk_bf16_f32
__device__ __forceinline__ unsigned pk2(float a, float b) {
  float2 f2; f2.x = a; f2.y = b;
  __hip_bfloat162 h = __float22bfloat162_rn(f2);
  union { __hip_bfloat162 h2; unsigned u; } cv; cv.h2 = h;
  return cv.u;
}
__device__ __forceinline__ float bfl(unsigned u) { return __uint_as_float(u << 16); }
__device__ __forceinline__ float bfh(unsigned u) { return __uint_as_float(u & 0xFFFF0000u); }

// ---- K0: prep — weights->bf16 with scales folded (x-transpose fused into qkv) ----
__global__ __launch_bounds__(256) void prep_kernel(
    const float* __restrict__ w_qk, const float* __restrict__ s_qk,
    const float* __restrict__ w_in, const float* __restrict__ s_in,
    const float* __restrict__ w_out, const float* __restrict__ s_out,
    unsigned short* __restrict__ wqkb, unsigned short* __restrict__ wob) {
  const int blk = blockIdx.x, tid = threadIdx.x;
  if (blk < 8) {
    const int r0 = blk * 48;
    for (int i = tid; i < 6144; i += 256) {
      int r = r0 + (i >> 7), c = i & 127;
      float wv, sv;
      if (r < 2 * CC) { wv = w_qk[r * CC + c]; sv = s_qk[r] * (r < CC ? QSCL : 1.0f); }
      else           { wv = w_in[(r - 2 * CC) * CC + c]; sv = s_in[r - 2 * CC]; }
      wqkb[r * CC + c] = f2bf(wv * sv);
    }
  } else {
    const int r0 = (blk - 8) * 64;
    for (int i = tid; i < 8192; i += 256) {
      int r = r0 + (i >> 7), c = i & 127;
      wob[r * CC + c] = f2bf(w_out[r * CC + c] * s_out[r]);
    }
  }
}

// ---- K1: qkv as MFMA GEMM (384 x 6400 x K=128), x transposed in-block via LDS ----
__global__ __launch_bounds__(256) void qkv_kernel(
    const float* __restrict__ x, const unsigned short* __restrict__ wqkb,
    const float* __restrict__ t_qk, const float* __restrict__ t_in,
    unsigned short* __restrict__ qt, unsigned short* __restrict__ kt,
    unsigned short* __restrict__ vb) {
  __shared__ __align__(16) unsigned short xb[16 * XROW];  // 4352 B
  const int tid = threadIdx.x;
  const int w = tid >> 6, lane = tid & 63, lo = lane & 15, g = lane >> 4;
  const int blk = blockIdx.x;
  const int b = blk / 400, pt = blk - b * 400;
  const int ng0 = pt * 16;
  const int a = ng0 / NAa, na0 = ng0 - a * NAa;
  const int be = b * 4 + a;
  // ---- stage: transpose x[b][c][ng0..ng0+15] f32 -> xb[n][c] bf16 ----
  {
    const int c = tid >> 1, half = tid & 1;
    const float* xr = &x[((size_t)(b * CC + c)) * NN + ng0 + 8 * half];
    const float4 f0 = *(const float4*)xr;
    const float4 f1 = *(const float4*)(xr + 4);
    unsigned short* dst = &xb[(8 * half) * XROW + c];
    dst[0 * XROW] = f2bf(f0.x); dst[1 * XROW] = f2bf(f0.y);
    dst[2 * XROW] = f2bf(f0.z); dst[3 * XROW] = f2bf(f0.w);
    dst[4 * XROW] = f2bf(f1.x); dst[5 * XROW] = f2bf(f1.y);
    dst[6 * XROW] = f2bf(f1.z); dst[7 * XROW] = f2bf(f1.w);
  }
  __syncthreads();
  bfrag8 bf[4];
#pragma unroll
  for (int kk = 0; kk < 4; kk++) bf[kk] = *(const bfrag8*)&xb[lo * XROW + kk * 32 + g * 8];
#pragma unroll
  for (int mt6 = 0; mt6 < 6; mt6++) {
    const int rowbase = (w * 6 + mt6) * 16;
    ffrag4 d = {0.f, 0.f, 0.f, 0.f};
#pragma unroll
    for (int kk = 0; kk < 4; kk++) {
      bfrag8 af = *(const bfrag8*)&wqkb[(size_t)(rowbase + lo) * CC + kk * 32 + g * 8];
      d = __builtin_amdgcn_mfma_f32_16x16x32_bf16(af, bf[kk], d, 0, 0, 0);
    }
    const int r0c = rowbase + 4 * g;
    if (r0c < CC) {
      const int h = r0c >> 5, d0 = r0c & 31;
      uint2 pk;
      pk.x = pk2(d[0] + t_qk[r0c] * QSCL, d[1] + t_qk[r0c + 1] * QSCL);
      pk.y = pk2(d[2] + t_qk[r0c + 2] * QSCL, d[3] + t_qk[r0c + 3] * QSCL);
      *(uint2*)&qt[((size_t)(be * HEADS + h) * NAa + na0 + lo) * HD + d0] = pk;
    } else if (r0c < 2 * CC) {
      const int ch = r0c - CC, h = ch >> 5, d0 = ch & 31;
      uint2 pk;
      pk.x = pk2(d[0] + t_qk[r0c], d[1] + t_qk[r0c + 1]);
      pk.y = pk2(d[2] + t_qk[r0c + 2], d[3] + t_qk[r0c + 3]);
      *(uint2*)&kt[((size_t)(be * HEADS + h) * NAa + na0 + lo) * HD + d0] = pk;
    } else {
      const int ch0 = r0c - 2 * CC;
      const uint2 xv = *(const uint2*)&xb[lo * XROW + ch0];
      float xr[4] = {bfl(xv.x), bfh(xv.x), bfl(xv.y), bfh(xv.y)};
#pragma unroll
      for (int r = 0; r < 4; r++) {
        float y = d[r] + t_in[ch0 + r];
        vb[((size_t)be * CC + ch0 + r) * NAa + na0 + lo] = f2bf(sigmoid_fast(y) * xr[r]);
      }
    }
  }
}

// ---- K2a: partial softmax denominators (M0 = 0, q pre-scaled) ----
__global__ __launch_bounds__(256) void stats_kernel(
    const unsigned short* __restrict__ qt, const unsigned short* __restrict__ kt,
    float* __restrict__ pstats) {
  int tid = threadIdx.x;
  int h = tid >> 6, lane = tid & 63, lo = lane & 15, g = lane >> 4;
  int bid = blockIdx.x;
  int be = bid & 7;
  int rest = bid >> 3;
  int n0 = (rest % 100) * 16;
  int split = rest / 100;
  int ts0 = split ? 12 : 0, ts1 = split ? 25 : 12;

  const unsigned short* qtb = qt + (size_t)(be * HEADS + h) * NAa * HD;
  const unsigned short* ktb = kt + (size_t)(be * HEADS + h) * NAa * HD;

  bfrag8 qf = *(const bfrag8*)(qtb + (size_t)(n0 + lo) * HD + g * 8);
  float sm[4] = {0.f, 0.f, 0.f, 0.f};
  for (int t = ts0; t < ts1; t++) {
    int m0 = t * MT;
#pragma unroll
    for (int sb = 0; sb < 4; sb++) {
      bfrag8 kf = *(const bfrag8*)(ktb + (size_t)(m0 + sb * 16 + lo) * HD + g * 8);
      ffrag4 z = {0.f, 0.f, 0.f, 0.f};
      ffrag4 c = __builtin_amdgcn_mfma_f32_16x16x32_bf16(qf, kf, z, 0, 0, 0);
#pragma unroll
      for (int r = 0; r < 4; r++) sm[r] += __builtin_amdgcn_exp2f(c[r]);
    }
  }
#pragma unroll
  for (int r = 0; r < 4; r++) {
#pragma unroll
    for (int off = 1; off <= 8; off <<= 1) sm[r] += __shfl_xor(sm[r], off);
  }
  if (lo == 0) {
    float4 s4; s4.x = sm[0]; s4.y = sm[1]; s4.z = sm[2]; s4.w = sm[3];
    *(float4*)&pstats[((size_t)(split * 8 + be) * HEADS + h) * NAa + n0 + 4 * g] = s4;
  }
}

// ---- K2b: apply — NB=32 tile, SINGLE-buffered P + parity halo buffer Hb.
//      Softmax denominator folded into MFMA C-in: c = QK + (-log2 den), P = exp2(c).
//      Schedule per tile: [conv(t): read P,Hb -> write A2] |bar|
//                         [QK(t+1): write P,Hb ; PV(t): read A2] |bar|
//      LDS 39.2 KB -> 4 blocks/CU; no min-waves hint (R3 spill lesson). ----
__global__ __launch_bounds__(512) void apply_kernel(
    const unsigned short* __restrict__ qt, const unsigned short* __restrict__ kt,
    const unsigned short* __restrict__ vb, const float* __restrict__ pstats,
    const float* __restrict__ w_fg, const float* __restrict__ s_fg,
    const float* __restrict__ t_fg, unsigned short* __restrict__ o_part) {
  __shared__ __align__(16) unsigned short Ps[2 * PW];   // 17536 B (cols' 0..63 = keys m0..m0+63)
  __shared__ __align__(16) unsigned short A2s[2 * AW];  // 19584 B
  __shared__ __align__(16) unsigned short Hb[1024];     //  2048 B halo [par][qs][h][lo][4]
  const int tid = threadIdx.x;
  const int w = tid >> 6, lane = tid & 63, lo = lane & 15, g = lane >> 4;
  const int h = w >> 1, u = w & 1;
  const int bid = blockIdx.x;
  const int be = bid & 7;
  const int rest = bid >> 3;
  const int n0 = (rest % 50) * NB;
  const int split = rest / 50;
  const int ts0 = split ? 12 : 0;
  const int tend = split ? 26 : 12;   // t=25 is a virtual tail tile

  const unsigned short* qtb = qt + (size_t)(be * HEADS + h) * NAa * HD;
  const unsigned short* ktb = kt + (size_t)(be * HEADS + h) * NAa * HD;
  const unsigned short* vhb = vb + (size_t)(be * CC + h * HD) * NAa;

  bfrag8 qf[2];
#pragma unroll
  for (int qs = 0; qs < 2; ++qs)
    qf[qs] = *(const bfrag8*)(qtb + (size_t)(n0 + 16 * qs + lo) * HD + g * 8);

  // conv-weight A-fragment (constant): row=lo=(ho*4+s), k=g*8+j
  bfrag8 wfrag;
  {
    const int ho = lo >> 2, s = lo & 3;
#pragma unroll
    for (int j = 0; j < 8; j++) {
      const int tp = j - s;
      float wv = (tp >= 0 && tp < 5) ? w_fg[(ho * HEADS + g) * 5 + tp] : 0.0f;
      wfrag[j] = (short)f2bf(wv);
    }
  }
  const float sfv = s_fg[g], tfv = t_fg[g];

  // -log2(denominator) per q-subtile, folded into QK's MFMA accumulator
  float linv[2];
#pragma unroll
  for (int qs = 0; qs < 2; ++qs) {
    const float den = pstats[((size_t)(0 + be) * HEADS + h) * NAa + n0 + 16 * qs + lo] +
                      pstats[((size_t)(8 + be) * HEADS + h) * NAa + n0 + 16 * qs + lo];
    linv[qs] = -__log2f(den);
  }

  ffrag4 oacc[2][2];
#pragma unroll
  for (int qs = 0; qs < 2; ++qs) {
    ffrag4 z = {0.f, 0.f, 0.f, 0.f};
    oacc[qs][0] = z; oacc[qs][1] = z;
  }

  // ---- prologue: Hb[0] = halo for conv(ts0)  (ts0 is even for both splits) ----
  if (split == 0) {
    if (u == 0 && g == 0) {
      uint2 zz; zz.x = 0; zz.y = 0;
#pragma unroll
      for (int qs = 0; qs < 2; ++qs)
        *(uint2*)&Hb[HB_IDX(0, qs, h, lo)] = zz;
    }
  } else if (u == 0) {
    // halo keys 764..767 from K rows 752..767 (g==3 lanes hold m 764+r)
    bfrag8 kf = *(const bfrag8*)(ktb + (size_t)(752 + lo) * HD + g * 8);
#pragma unroll
    for (int qs = 0; qs < 2; ++qs) {
      ffrag4 cin = {linv[qs], linv[qs], linv[qs], linv[qs]};
      ffrag4 c = __builtin_amdgcn_mfma_f32_16x16x32_bf16(kf, qf[qs], cin, 0, 0, 0);
      if (g == 3) {
        uint2 pk;
        pk.x = pk2(__builtin_amdgcn_exp2f(c[0]), __builtin_amdgcn_exp2f(c[1]));
        pk.y = pk2(__builtin_amdgcn_exp2f(c[2]), __builtin_amdgcn_exp2f(c[3]));
        *(uint2*)&Hb[HB_IDX(0, qs, h, lo)] = pk;
      }
    }
  }
  // ---- prologue: QK(ts0) -> Ps; sb==3/g==3 lanes also feed Hb[1] (for conv(ts0+1)) ----
  {
    const int m0 = ts0 * MT;
#pragma unroll
    for (int sbi = 0; sbi < 2; sbi++) {
      const int sb = 2 * u + sbi;
      bfrag8 kf = *(const bfrag8*)(ktb + (size_t)(m0 + sb * 16 + lo) * HD + g * 8);
#pragma unroll
      for (int qs = 0; qs < 2; ++qs) {
        ffrag4 cin = {linv[qs], linv[qs], linv[qs], linv[qs]};
        ffrag4 c = __builtin_amdgcn_mfma_f32_16x16x32_bf16(kf, qf[qs], cin, 0, 0, 0);
        uint2 pk;
        pk.x = pk2(__builtin_amdgcn_exp2f(c[0]), __builtin_amdgcn_exp2f(c[1]));
        pk.y = pk2(__builtin_amdgcn_exp2f(c[2]), __builtin_amdgcn_exp2f(c[3]));
        *(uint2*)&Ps[qs * PW + h * P_HEAD + lo * P_ROW + 16 * sb + 4 * g] = pk;
        if (sb == 3 && g == 3)
          *(uint2*)&Hb[HB_IDX(1, qs, h, lo)] = pk;
      }
    }
  }
  __syncthreads();

  for (int t = ts0; t < tend; t++) {
    const int m0 = t * MT;
    const int par = t & 1;
    // early V loads (k-half u) for PV(t) — shared across q-subtiles
    const bfrag8 vf0 = *(const bfrag8*)(vhb + (size_t)lo * NAa + (m0 - 2 + 32 * u + 8 * g));
    const bfrag8 vf1 = *(const bfrag8*)(vhb + (size_t)(16 + lo) * NAa + (m0 - 2 + 32 * u + 8 * g));
    const bool doqk = (t + 1 < tend);
    const bool realqk = doqk && (t + 1 < 25);
    bfrag8 kf0, kf1;
    if (realqk) {
      const int m1 = (t + 1) * MT;
      kf0 = *(const bfrag8*)(ktb + (size_t)(m1 + (2 * u) * 16 + lo) * HD + g * 8);
      kf1 = *(const bfrag8*)(ktb + (size_t)(m1 + (2 * u + 1) * 16 + lo) * HD + g * 8);
    }
    // ---- phase 1: conv(t) reads Ps (cols' 4i-4..4i+3; i==0 low half from Hb) ----
    const bool edge = (t == 0) || (t == 25);
#pragma unroll
    for (int qs = 0; qs < 2; ++qs) {
#pragma unroll
      for (int ii = 0; ii < 2; ii++) {
        const int i = 2 * w + ii;
        cvt16 bb;
        if (i == 0)
          bb.u2[0] = *(const uint2*)&Hb[HB_IDX(par, qs, g, lo)];
        else
          bb.u2[0] = *(const uint2*)&Ps[qs * PW + g * P_HEAD + lo * P_ROW + 4 * i - 4];
        bb.u2[1] = *(const uint2*)&Ps[qs * PW + g * P_HEAD + lo * P_ROW + 4 * i];
        ffrag4 z = {0.f, 0.f, 0.f, 0.f};
        ffrag4 d = __builtin_amdgcn_mfma_f32_16x16x32_bf16(wfrag, bb.f8, z, 0, 0, 0);
        float a2v[4];
        if (edge) {
#pragma unroll
          for (int r = 0; r < 4; r++) {
            const int mp = m0 - 2 + 4 * i + r;
            float y = d[r] * sfv + tfv;
            float v = y * sigmoid_fast(y);
            a2v[r] = (mp >= 0 && mp < NAa) ? v : 0.0f;
          }
        } else {
#pragma unroll
          for (int r = 0; r < 4; r++) {
            float y = d[r] * sfv + tfv;
            a2v[r] = y * sigmoid_fast(y);
          }
        }
        uint2 pk;
        pk.x = pk2(a2v[0], a2v[1]);
        pk.y = pk2(a2v[2], a2v[3]);
        *(uint2*)&A2s[qs * AW + g * A_HEAD + lo * A_ROW + 4 * i] = pk;
      }
    }
    __syncthreads();
    // ---- phase 2: QK(t+1) -> Ps/Hb, then PV(t) reads A2s ----
    if (doqk) {
      if (realqk) {
#pragma unroll
        for (int qs = 0; qs < 2; ++qs) {
          ffrag4 cin = {linv[qs], linv[qs], linv[qs], linv[qs]};
          ffrag4 c0 = __builtin_amdgcn_mfma_f32_16x16x32_bf16(kf0, qf[qs], cin, 0, 0, 0);
          ffrag4 c1 = __builtin_amdgcn_mfma_f32_16x16x32_bf16(kf1, qf[qs], cin, 0, 0, 0);
          uint2 pk;
          pk.x = pk2(__builtin_amdgcn_exp2f(c0[0]), __builtin_amdgcn_exp2f(c0[1]));
          pk.y = pk2(__builtin_amdgcn_exp2f(c0[2]), __builtin_amdgcn_exp2f(c0[3]));
          *(uint2*)&Ps[qs * PW + h * P_HEAD + lo * P_ROW + 16 * (2 * u) + 4 * g] = pk;
          uint2 pk1;
          pk1.x = pk2(__builtin_amdgcn_exp2f(c1[0]), __builtin_amdgcn_exp2f(c1[1]));
          pk1.y = pk2(__builtin_amdgcn_exp2f(c1[2]), __builtin_amdgcn_exp2f(c1[3]));
          *(uint2*)&Ps[qs * PW + h * P_HEAD + lo * P_ROW + 16 * (2 * u + 1) + 4 * g] = pk1;
          if (u == 1 && g == 3)
            *(uint2*)&Hb[HB_IDX(par, qs, h, lo)] = pk1;   // halo for conv(t+2)
        }
      } else {
        uint2 zz; zz.x = 0; zz.y = 0;
#pragma unroll
        for (int qs = 0; qs < 2; ++qs) {
          *(uint2*)&Ps[qs * PW + h * P_HEAD + lo * P_ROW + 16 * (2 * u) + 4 * g] = zz;
          *(uint2*)&Ps[qs * PW + h * P_HEAD + lo * P_ROW + 16 * (2 * u + 1) + 4 * g] = zz;
        }
      }
    }
    // PV(t): head h, k-half u, both qsubs (V frags shared)
#pragma unroll
    for (int qs = 0; qs < 2; ++qs) {
      cvt16 av;
      av.u2[0] = *(const uint2*)&A2s[qs * AW + h * A_HEAD + lo * A_ROW + 32 * u + 8 * g];
      av.u2[1] = *(const uint2*)&A2s[qs * AW + h * A_HEAD + lo * A_ROW + 32 * u + 8 * g + 4];
      oacc[qs][0] = __builtin_amdgcn_mfma_f32_16x16x32_bf16(av.f8, vf0, oacc[qs][0], 0, 0, 0);
      oacc[qs][1] = __builtin_amdgcn_mfma_f32_16x16x32_bf16(av.f8, vf1, oacc[qs][1], 0, 0, 0);
    }
    __syncthreads();
  }

  // ---- cross-u reduction via A2s scratch, write o_part [split][be][n][c] bf16 ----
  float* scr = (float*)A2s;
  if (u == 1) {
#pragma unroll
    for (int qs = 0; qs < 2; ++qs) {
      float4 f0; f0.x = oacc[qs][0][0]; f0.y = oacc[qs][0][1]; f0.z = oacc[qs][0][2]; f0.w = oacc[qs][0][3];
      float4 f1; f1.x = oacc[qs][1][0]; f1.y = oacc[qs][1][1]; f1.z = oacc[qs][1][2]; f1.w = oacc[qs][1][3];
      *(float4*)&scr[((qs * 4 + h) * 64 + lane) * 8] = f0;
      *(float4*)&scr[((qs * 4 + h) * 64 + lane) * 8 + 4] = f1;
    }
  }
  __syncthreads();
  if (u == 0) {
#pragma unroll
    for (int qs = 0; qs < 2; ++qs) {
      const float4 f0 = *(const float4*)&scr[((qs * 4 + h) * 64 + lane) * 8];
      const float4 f1 = *(const float4*)&scr[((qs * 4 + h) * 64 + lane) * 8 + 4];
      const float fa[4] = {f0.x, f0.y, f0.z, f0.w};
      const float fb[4] = {f1.x, f1.y, f1.z, f1.w};
#pragma unroll
      for (int r = 0; r < 4; r++) {
        const size_t rowoff = ((size_t)(split * 8 + be) * NAa + n0 + 16 * qs + 4 * g + r) * CC;
        o_part[rowoff + h * HD + lo] = f2bf(oacc[qs][0][r] + fa[r]);
        o_part[rowoff + h * HD + 16 + lo] = f2bf(oacc[qs][1][r] + fb[r]);
      }
    }
  }
}

// ---- K3: out as MFMA GEMM + SiLU-gate + residual ----
__global__ __launch_bounds__(256) void out_kernel(
    const unsigned short* __restrict__ o_part, const unsigned short* __restrict__ wob,
    const float* __restrict__ t_out, const float* __restrict__ x,
    float* __restrict__ out) {
  const int tid = threadIdx.x;
  const int w = tid >> 6, lane = tid & 63, lo = lane & 15, g = lane >> 4;
  const int blk = blockIdx.x;
  const int b = blk / 400, pt = blk - b * 400;
  const int ng0 = pt * 16;
  const int a = ng0 / NAa, na0 = ng0 - a * NAa;
  const int be = b * 4 + a;
  const size_t orow0 = ((size_t)(0 * 8 + be) * NAa + na0 + lo) * CC;
  const size_t orow1 = ((size_t)(1 * 8 + be) * NAa + na0 + lo) * CC;
  bfrag8 bf0[4], bf1[4];
#pragma unroll
  for (int kk = 0; kk < 4; kk++) {
    bf0[kk] = *(const bfrag8*)&o_part[orow0 + kk * 32 + g * 8];
    bf1[kk] = *(const bfrag8*)&o_part[orow1 + kk * 32 + g * 8];
  }
#pragma unroll
  for (int mt2 = 0; mt2 < 2; mt2++) {
    const int rowbase = (w * 2 + mt2) * 16;
    ffrag4 d = {0.f, 0.f, 0.f, 0.f};
#pragma unroll
    for (int kk = 0; kk < 4; kk++) {
      bfrag8 af = *(const bfrag8*)&wob[(size_t)(rowbase + lo) * CC + kk * 32 + g * 8];
      d = __builtin_amdgcn_mfma_f32_16x16x32_bf16(af, bf0[kk], d, 0, 0, 0);
      d = __builtin_amdgcn_mfma_f32_16x16x32_bf16(af, bf1[kk], d, 0, 0, 0);
    }
    const int ch0 = rowbase + 4 * g;
    const uint2 q0 = *(const uint2*)&o_part[orow0 + ch0];
    const uint2 q1 = *(const uint2*)&o_part[orow1 + ch0];
    float ov[4] = {bfl(q0.x) + bfl(q1.x), bfh(q0.x) + bfh(q1.x),
                   bfl(q0.y) + bfl(q1.y), bfh(q0.y) + bfh(q1.y)};
#pragma unroll
    for (int r = 0; r < 4; r++) {
      const size_t xi = ((size_t)b * CC + ch0 + r) * NN + ng0 + lo;
      float y = d[r] + t_out[ch0 + r];
      out[xi] = ov[r] * sigmoid_fast(y) + x[xi];
    }
  }
}

extern "C" void kernel_launch(void* const* d_in, const int* in_sizes, int n_in,
                              void* d_out, int out_size, void* d_ws, size_t ws_size,
                              hipStream_t stream) {
  const float* x    = (const float*)d_in[0];
  const float* w_qk = (const float*)d_in[1];
  const float* s_qk = (const float*)d_in[2];
  const float* t_qk = (const float*)d_in[3];
  const float* w_in = (const float*)d_in[4];
  const float* s_in = (const float*)d_in[5];
  const float* t_in = (const float*)d_in[6];
  const float* w_out = (const float*)d_in[7];
  const float* s_out = (const float*)d_in[8];
  const float* t_out = (const float*)d_in[9];
  const float* w_fg = (const float*)d_in[10];
  const float* s_fg = (const float*)d_in[11];
  const float* t_fg = (const float*)d_in[12];

  char* wsb = (char*)d_ws;
  unsigned short* o_part = (unsigned short*)wsb;               // 6,553,600 B  [split][be][n][c] bf16
  unsigned short* vb_raw = (unsigned short*)(wsb + 6553600);   // 3,276,864 B
  unsigned short* vbp = vb_raw + 2;
  unsigned short* qt = (unsigned short*)(wsb + 9830464);       // 3,276,800 B
  unsigned short* kt = (unsigned short*)(wsb + 13107264);      // 3,276,800 B
  unsigned short* wqkb = (unsigned short*)(wsb + 19660864);    //    98,304 B
  unsigned short* wob = (unsigned short*)(wsb + 19759168);     //    32,768 B
  float* pstats = (float*)(wsb + 19791936);                    // 1,638,400 B
  float* out = (float*)d_out;

  prep_kernel<<<10, 256, 0, stream>>>(w_qk, s_qk, w_in, s_in, w_out, s_out, wqkb, wob);
  qkv_kernel<<<800, 256, 0, stream>>>(x, wqkb, t_qk, t_in, qt, kt, vbp);
  stats_kernel<<<1600, 256, 0, stream>>>(qt, kt, pstats);
  apply_kernel<<<800, 512, 0, stream>>>(qt, kt, vbp, pstats, w_fg, s_fg, t_fg, o_part);
  out_kernel<<<800, 256, 0, stream>>>(o_part, wob, t_out, x, out);
}

// Round 6
// 128.863 us; speedup vs baseline: 1.8087x; 1.0075x over previous
//
#include <hip/hip_runtime.h>
#include <hip/hip_bf16.h>
#include <cstdint>

#define CC 128
#define NN 6400
#define NAa 1600
#define HEADS 4
#define HD 32
#define NB 32
#define MT 64

#define P_ROW 68
#define P_HEAD 1096   // 16*68+8 pad
#define A_ROW 76
#define A_HEAD 1224   // 16*76+8 pad
#define PW (HEADS * P_HEAD)   // 4384 elems per q-subtile
#define AW (HEADS * A_HEAD)   // 4896 elems per q-subtile
// halo buffer: [parity][qs][h][lo][4] bf16
#define HB_IDX(par, qs, hh, lo) (((((par)*2 + (qs))*4 + (hh))*16 + (lo)) * 4)
#define XROW 136              // qkv LDS x-tile row stride (16B-aligned: 272 B)

typedef __attribute__((ext_vector_type(8))) short bfrag8;
typedef __attribute__((ext_vector_type(4))) float ffrag4;
typedef union { uint2 u2[2]; bfrag8 f8; } cvt16;

#define LOG2E 1.4426950408889634f
#define QSCL (0.17677669529663687f * 1.4426950408889634f)

__device__ __forceinline__ float sigmoid_fast(float y) {
  return __builtin_amdgcn_rcpf(1.0f + __builtin_amdgcn_exp2f(-LOG2E * y));
}
__device__ __forceinline__ unsigned short f2bf(float f) {
  unsigned u = __float_as_uint(f);
  return (unsigned short)((u + 0x7FFFu + ((u >> 16) & 1u)) >> 16);
}
// packed 2xf32 -> 2xbf16 (RNE) — should emit v_cvt_pk_bf16_f32
__device__ __forceinline__ unsigned pk2(float a, float b) {
  float2 f2; f2.x = a; f2.y = b;
  __hip_bfloat162 h = __float22bfloat162_rn(f2);
  union { __hip_bfloat162 h2; unsigned u; } cv; cv.h2 = h;
  return cv.u;
}
__device__ __forceinline__ float bfl(unsigned u) { return __uint_as_float(u << 16); }
__device__ __forceinline__ float bfh(unsigned u) { return __uint_as_float(u & 0xFFFF0000u); }

// ---- K0: prep — weights->bf16 with scales folded (x-transpose fused into qkv) ----
__global__ __launch_bounds__(256) void prep_kernel(
    const float* __restrict__ w_qk, const float* __restrict__ s_qk,
    const float* __restrict__ w_in, const float* __restrict__ s_in,
    const float* __restrict__ w_out, const float* __restrict__ s_out,
    unsigned short* __restrict__ wqkb, unsigned short* __restrict__ wob) {
  const int blk = blockIdx.x, tid = threadIdx.x;
  if (blk < 8) {
    const int r0 = blk * 48;
    for (int i = tid; i < 6144; i += 256) {
      int r = r0 + (i >> 7), c = i & 127;
      float wv, sv;
      if (r < 2 * CC) { wv = w_qk[r * CC + c]; sv = s_qk[r] * (r < CC ? QSCL : 1.0f); }
      else           { wv = w_in[(r - 2 * CC) * CC + c]; sv = s_in[r - 2 * CC]; }
      wqkb[r * CC + c] = f2bf(wv * sv);
    }
  } else {
    const int r0 = (blk - 8) * 64;
    for (int i = tid; i < 8192; i += 256) {
      int r = r0 + (i >> 7), c = i & 127;
      wob[r * CC + c] = f2bf(w_out[r * CC + c] * s_out[r]);
    }
  }
}

// ---- K1: qkv as MFMA GEMM (384 x 6400 x K=128), x transposed in-block via LDS ----
__global__ __launch_bounds__(256) void qkv_kernel(
    const float* __restrict__ x, const unsigned short* __restrict__ wqkb,
    const float* __restrict__ t_qk, const float* __restrict__ t_in,
    unsigned short* __restrict__ qt, unsigned short* __restrict__ kt,
    unsigned short* __restrict__ vb) {
  __shared__ __align__(16) unsigned short xb[16 * XROW];  // 4352 B
  const int tid = threadIdx.x;
  const int w = tid >> 6, lane = tid & 63, lo = lane & 15, g = lane >> 4;
  const int blk = blockIdx.x;
  const int b = blk / 400, pt = blk - b * 400;
  const int ng0 = pt * 16;
  const int a = ng0 / NAa, na0 = ng0 - a * NAa;
  const int be = b * 4 + a;
  // ---- stage: transpose x[b][c][ng0..ng0+15] f32 -> xb[n][c] bf16 ----
  {
    const int c = tid >> 1, half = tid & 1;
    const float* xr = &x[((size_t)(b * CC + c)) * NN + ng0 + 8 * half];
    const float4 f0 = *(const float4*)xr;
    const float4 f1 = *(const float4*)(xr + 4);
    unsigned short* dst = &xb[(8 * half) * XROW + c];
    dst[0 * XROW] = f2bf(f0.x); dst[1 * XROW] = f2bf(f0.y);
    dst[2 * XROW] = f2bf(f0.z); dst[3 * XROW] = f2bf(f0.w);
    dst[4 * XROW] = f2bf(f1.x); dst[5 * XROW] = f2bf(f1.y);
    dst[6 * XROW] = f2bf(f1.z); dst[7 * XROW] = f2bf(f1.w);
  }
  __syncthreads();
  bfrag8 bf[4];
#pragma unroll
  for (int kk = 0; kk < 4; kk++) bf[kk] = *(const bfrag8*)&xb[lo * XROW + kk * 32 + g * 8];
#pragma unroll
  for (int mt6 = 0; mt6 < 6; mt6++) {
    const int rowbase = (w * 6 + mt6) * 16;
    ffrag4 d = {0.f, 0.f, 0.f, 0.f};
#pragma unroll
    for (int kk = 0; kk < 4; kk++) {
      bfrag8 af = *(const bfrag8*)&wqkb[(size_t)(rowbase + lo) * CC + kk * 32 + g * 8];
      d = __builtin_amdgcn_mfma_f32_16x16x32_bf16(af, bf[kk], d, 0, 0, 0);
    }
    const int r0c = rowbase + 4 * g;
    if (r0c < CC) {
      const int h = r0c >> 5, d0 = r0c & 31;
      uint2 pk;
      pk.x = pk2(d[0] + t_qk[r0c] * QSCL, d[1] + t_qk[r0c + 1] * QSCL);
      pk.y = pk2(d[2] + t_qk[r0c + 2] * QSCL, d[3] + t_qk[r0c + 3] * QSCL);
      *(uint2*)&qt[((size_t)(be * HEADS + h) * NAa + na0 + lo) * HD + d0] = pk;
    } else if (r0c < 2 * CC) {
      const int ch = r0c - CC, h = ch >> 5, d0 = ch & 31;
      uint2 pk;
      pk.x = pk2(d[0] + t_qk[r0c], d[1] + t_qk[r0c + 1]);
      pk.y = pk2(d[2] + t_qk[r0c + 2], d[3] + t_qk[r0c + 3]);
      *(uint2*)&kt[((size_t)(be * HEADS + h) * NAa + na0 + lo) * HD + d0] = pk;
    } else {
      const int ch0 = r0c - 2 * CC;
      const uint2 xv = *(const uint2*)&xb[lo * XROW + ch0];
      float xr[4] = {bfl(xv.x), bfh(xv.x), bfl(xv.y), bfh(xv.y)};
#pragma unroll
      for (int r = 0; r < 4; r++) {
        float y = d[r] + t_in[ch0 + r];
        vb[((size_t)be * CC + ch0 + r) * NAa + na0 + lo] = f2bf(sigmoid_fast(y) * xr[r]);
      }
    }
  }
}

// ---- K2a: partial softmax denominators (M0 = 0, q pre-scaled) ----
//      Widened to 32 queries/block: each kf B-fragment feeds two MFMAs,
//      halving K loads + addressing per unit work (stats was ~2nd biggest kernel).
__global__ __launch_bounds__(256) void stats_kernel(
    const unsigned short* __restrict__ qt, const unsigned short* __restrict__ kt,
    float* __restrict__ pstats) {
  int tid = threadIdx.x;
  int h = tid >> 6, lane = tid & 63, lo = lane & 15, g = lane >> 4;
  int bid = blockIdx.x;
  int be = bid & 7;
  int rest = bid >> 3;
  int n0 = (rest % 50) * 32;
  int split = rest / 50;
  int ts0 = split ? 12 : 0, ts1 = split ? 25 : 12;

  const unsigned short* qtb = qt + (size_t)(be * HEADS + h) * NAa * HD;
  const unsigned short* ktb = kt + (size_t)(be * HEADS + h) * NAa * HD;

  bfrag8 qf0 = *(const bfrag8*)(qtb + (size_t)(n0 + lo) * HD + g * 8);
  bfrag8 qf1 = *(const bfrag8*)(qtb + (size_t)(n0 + 16 + lo) * HD + g * 8);
  float sm0[4] = {0.f, 0.f, 0.f, 0.f};
  float sm1[4] = {0.f, 0.f, 0.f, 0.f};
  for (int t = ts0; t < ts1; t++) {
    int m0 = t * MT;
#pragma unroll
    for (int sb = 0; sb < 4; sb++) {
      bfrag8 kf = *(const bfrag8*)(ktb + (size_t)(m0 + sb * 16 + lo) * HD + g * 8);
      ffrag4 z = {0.f, 0.f, 0.f, 0.f};
      ffrag4 c0 = __builtin_amdgcn_mfma_f32_16x16x32_bf16(qf0, kf, z, 0, 0, 0);
      ffrag4 c1 = __builtin_amdgcn_mfma_f32_16x16x32_bf16(qf1, kf, z, 0, 0, 0);
#pragma unroll
      for (int r = 0; r < 4; r++) {
        sm0[r] += __builtin_amdgcn_exp2f(c0[r]);
        sm1[r] += __builtin_amdgcn_exp2f(c1[r]);
      }
    }
  }
#pragma unroll
  for (int r = 0; r < 4; r++) {
#pragma unroll
    for (int off = 1; off <= 8; off <<= 1) {
      sm0[r] += __shfl_xor(sm0[r], off);
      sm1[r] += __shfl_xor(sm1[r], off);
    }
  }
  if (lo == 0) {
    float4 s4; s4.x = sm0[0]; s4.y = sm0[1]; s4.z = sm0[2]; s4.w = sm0[3];
    *(float4*)&pstats[((size_t)(split * 8 + be) * HEADS + h) * NAa + n0 + 4 * g] = s4;
    float4 s5; s5.x = sm1[0]; s5.y = sm1[1]; s5.z = sm1[2]; s5.w = sm1[3];
    *(float4*)&pstats[((size_t)(split * 8 + be) * HEADS + h) * NAa + n0 + 16 + 4 * g] = s5;
  }
}

// ---- K2b: apply — NB=32 tile, SINGLE-buffered P + parity halo buffer Hb.
//      Softmax denominator folded into MFMA C-in: c = QK + (-log2 den), P = exp2(c).
//      s_setprio(1) around MFMA clusters (T5): phase-split schedule with 3-4
//      resident blocks/CU at different t -> scheduler favors MFMA-entering waves.
//      LDS 39.2 KB -> 4 blocks/CU; no min-waves hint (R3 spill lesson). ----
__global__ __launch_bounds__(512) void apply_kernel(
    const unsigned short* __restrict__ qt, const unsigned short* __restrict__ kt,
    const unsigned short* __restrict__ vb, const float* __restrict__ pstats,
    const float* __restrict__ w_fg, const float* __restrict__ s_fg,
    const float* __restrict__ t_fg, unsigned short* __restrict__ o_part) {
  __shared__ __align__(16) unsigned short Ps[2 * PW];   // 17536 B (cols' 0..63 = keys m0..m0+63)
  __shared__ __align__(16) unsigned short A2s[2 * AW];  // 19584 B
  __shared__ __align__(16) unsigned short Hb[1024];     //  2048 B halo [par][qs][h][lo][4]
  const int tid = threadIdx.x;
  const int w = tid >> 6, lane = tid & 63, lo = lane & 15, g = lane >> 4;
  const int h = w >> 1, u = w & 1;
  const int bid = blockIdx.x;
  const int be = bid & 7;
  const int rest = bid >> 3;
  const int n0 = (rest % 50) * NB;
  const int split = rest / 50;
  const int ts0 = split ? 12 : 0;
  const int tend = split ? 26 : 12;   // t=25 is a virtual tail tile

  const unsigned short* qtb = qt + (size_t)(be * HEADS + h) * NAa * HD;
  const unsigned short* ktb = kt + (size_t)(be * HEADS + h) * NAa * HD;
  const unsigned short* vhb = vb + (size_t)(be * CC + h * HD) * NAa;

  bfrag8 qf[2];
#pragma unroll
  for (int qs = 0; qs < 2; ++qs)
    qf[qs] = *(const bfrag8*)(qtb + (size_t)(n0 + 16 * qs + lo) * HD + g * 8);

  // conv-weight A-fragment (constant): row=lo=(ho*4+s), k=g*8+j
  bfrag8 wfrag;
  {
    const int ho = lo >> 2, s = lo & 3;
#pragma unroll
    for (int j = 0; j < 8; j++) {
      const int tp = j - s;
      float wv = (tp >= 0 && tp < 5) ? w_fg[(ho * HEADS + g) * 5 + tp] : 0.0f;
      wfrag[j] = (short)f2bf(wv);
    }
  }
  const float sfv = s_fg[g], tfv = t_fg[g];

  // -log2(denominator) per q-subtile, folded into QK's MFMA accumulator
  float linv[2];
#pragma unroll
  for (int qs = 0; qs < 2; ++qs) {
    const float den = pstats[((size_t)(0 + be) * HEADS + h) * NAa + n0 + 16 * qs + lo] +
                      pstats[((size_t)(8 + be) * HEADS + h) * NAa + n0 + 16 * qs + lo];
    linv[qs] = -__log2f(den);
  }

  ffrag4 oacc[2][2];
#pragma unroll
  for (int qs = 0; qs < 2; ++qs) {
    ffrag4 z = {0.f, 0.f, 0.f, 0.f};
    oacc[qs][0] = z; oacc[qs][1] = z;
  }

  // ---- prologue: Hb[0] = halo for conv(ts0)  (ts0 is even for both splits) ----
  if (split == 0) {
    if (u == 0 && g == 0) {
      uint2 zz; zz.x = 0; zz.y = 0;
#pragma unroll
      for (int qs = 0; qs < 2; ++qs)
        *(uint2*)&Hb[HB_IDX(0, qs, h, lo)] = zz;
    }
  } else if (u == 0) {
    // halo keys 764..767 from K rows 752..767 (g==3 lanes hold m 764+r)
    bfrag8 kf = *(const bfrag8*)(ktb + (size_t)(752 + lo) * HD + g * 8);
#pragma unroll
    for (int qs = 0; qs < 2; ++qs) {
      ffrag4 cin = {linv[qs], linv[qs], linv[qs], linv[qs]};
      ffrag4 c = __builtin_amdgcn_mfma_f32_16x16x32_bf16(kf, qf[qs], cin, 0, 0, 0);
      if (g == 3) {
        uint2 pk;
        pk.x = pk2(__builtin_amdgcn_exp2f(c[0]), __builtin_amdgcn_exp2f(c[1]));
        pk.y = pk2(__builtin_amdgcn_exp2f(c[2]), __builtin_amdgcn_exp2f(c[3]));
        *(uint2*)&Hb[HB_IDX(0, qs, h, lo)] = pk;
      }
    }
  }
  // ---- prologue: QK(ts0) -> Ps; sb==3/g==3 lanes also feed Hb[1] (for conv(ts0+1)) ----
  {
    const int m0 = ts0 * MT;
#pragma unroll
    for (int sbi = 0; sbi < 2; sbi++) {
      const int sb = 2 * u + sbi;
      bfrag8 kf = *(const bfrag8*)(ktb + (size_t)(m0 + sb * 16 + lo) * HD + g * 8);
#pragma unroll
      for (int qs = 0; qs < 2; ++qs) {
        ffrag4 cin = {linv[qs], linv[qs], linv[qs], linv[qs]};
        ffrag4 c = __builtin_amdgcn_mfma_f32_16x16x32_bf16(kf, qf[qs], cin, 0, 0, 0);
        uint2 pk;
        pk.x = pk2(__builtin_amdgcn_exp2f(c[0]), __builtin_amdgcn_exp2f(c[1]));
        pk.y = pk2(__builtin_amdgcn_exp2f(c[2]), __builtin_amdgcn_exp2f(c[3]));
        *(uint2*)&Ps[qs * PW + h * P_HEAD + lo * P_ROW + 16 * sb + 4 * g] = pk;
        if (sb == 3 && g == 3)
          *(uint2*)&Hb[HB_IDX(1, qs, h, lo)] = pk;
      }
    }
  }
  __syncthreads();

  for (int t = ts0; t < tend; t++) {
    const int m0 = t * MT;
    const int par = t & 1;
    // early V loads (k-half u) for PV(t) — shared across q-subtiles
    const bfrag8 vf0 = *(const bfrag8*)(vhb + (size_t)lo * NAa + (m0 - 2 + 32 * u + 8 * g));
    const bfrag8 vf1 = *(const bfrag8*)(vhb + (size_t)(16 + lo) * NAa + (m0 - 2 + 32 * u + 8 * g));
    const bool doqk = (t + 1 < tend);
    const bool realqk = doqk && (t + 1 < 25);
    bfrag8 kf0, kf1;
    if (realqk) {
      const int m1 = (t + 1) * MT;
      kf0 = *(const bfrag8*)(ktb + (size_t)(m1 + (2 * u) * 16 + lo) * HD + g * 8);
      kf1 = *(const bfrag8*)(ktb + (size_t)(m1 + (2 * u + 1) * 16 + lo) * HD + g * 8);
    }
    // ---- phase 1: conv(t) reads Ps (cols' 4i-4..4i+3; i==0 low half from Hb) ----
    const bool edge = (t == 0) || (t == 25);
#pragma unroll
    for (int qs = 0; qs < 2; ++qs) {
#pragma unroll
      for (int ii = 0; ii < 2; ii++) {
        const int i = 2 * w + ii;
        cvt16 bb;
        if (i == 0)
          bb.u2[0] = *(const uint2*)&Hb[HB_IDX(par, qs, g, lo)];
        else
          bb.u2[0] = *(const uint2*)&Ps[qs * PW + g * P_HEAD + lo * P_ROW + 4 * i - 4];
        bb.u2[1] = *(const uint2*)&Ps[qs * PW + g * P_HEAD + lo * P_ROW + 4 * i];
        __builtin_amdgcn_s_setprio(1);
        ffrag4 z = {0.f, 0.f, 0.f, 0.f};
        ffrag4 d = __builtin_amdgcn_mfma_f32_16x16x32_bf16(wfrag, bb.f8, z, 0, 0, 0);
        __builtin_amdgcn_s_setprio(0);
        float a2v[4];
        if (edge) {
#pragma unroll
          for (int r = 0; r < 4; r++) {
            const int mp = m0 - 2 + 4 * i + r;
            float y = d[r] * sfv + tfv;
            float v = y * sigmoid_fast(y);
            a2v[r] = (mp >= 0 && mp < NAa) ? v : 0.0f;
          }
        } else {
#pragma unroll
          for (int r = 0; r < 4; r++) {
            float y = d[r] * sfv + tfv;
            a2v[r] = y * sigmoid_fast(y);
          }
        }
        uint2 pk;
        pk.x = pk2(a2v[0], a2v[1]);
        pk.y = pk2(a2v[2], a2v[3]);
        *(uint2*)&A2s[qs * AW + g * A_HEAD + lo * A_ROW + 4 * i] = pk;
      }
    }
    __syncthreads();
    // ---- phase 2: QK(t+1) -> Ps/Hb, then PV(t) reads A2s ----
    if (doqk) {
      if (realqk) {
#pragma unroll
        for (int qs = 0; qs < 2; ++qs) {
          ffrag4 cin = {linv[qs], linv[qs], linv[qs], linv[qs]};
          __builtin_amdgcn_s_setprio(1);
          ffrag4 c0 = __builtin_amdgcn_mfma_f32_16x16x32_bf16(kf0, qf[qs], cin, 0, 0, 0);
          ffrag4 c1 = __builtin_amdgcn_mfma_f32_16x16x32_bf16(kf1, qf[qs], cin, 0, 0, 0);
          __builtin_amdgcn_s_setprio(0);
          uint2 pk;
          pk.x = pk2(__builtin_amdgcn_exp2f(c0[0]), __builtin_amdgcn_exp2f(c0[1]));
          pk.y = pk2(__builtin_amdgcn_exp2f(c0[2]), __builtin_amdgcn_exp2f(c0[3]));
          *(uint2*)&Ps[qs * PW + h * P_HEAD + lo * P_ROW + 16 * (2 * u) + 4 * g] = pk;
          uint2 pk1;
          pk1.x = pk2(__builtin_amdgcn_exp2f(c1[0]), __builtin_amdgcn_exp2f(c1[1]));
          pk1.y = pk2(__builtin_amdgcn_exp2f(c1[2]), __builtin_amdgcn_exp2f(c1[3]));
          *(uint2*)&Ps[qs * PW + h * P_HEAD + lo * P_ROW + 16 * (2 * u + 1) + 4 * g] = pk1;
          if (u == 1 && g == 3)
            *(uint2*)&Hb[HB_IDX(par, qs, h, lo)] = pk1;   // halo for conv(t+2)
        }
      } else {
        uint2 zz; zz.x = 0; zz.y = 0;
#pragma unroll
        for (int qs = 0; qs < 2; ++qs) {
          *(uint2*)&Ps[qs * PW + h * P_HEAD + lo * P_ROW + 16 * (2 * u) + 4 * g] = zz;
          *(uint2*)&Ps[qs * PW + h * P_HEAD + lo * P_ROW + 16 * (2 * u + 1) + 4 * g] = zz;
        }
      }
    }
    // PV(t): head h, k-half u, both qsubs (V frags shared)
#pragma unroll
    for (int qs = 0; qs < 2; ++qs) {
      cvt16 av;
      av.u2[0] = *(const uint2*)&A2s[qs * AW + h * A_HEAD + lo * A_ROW + 32 * u + 8 * g];
      av.u2[1] = *(const uint2*)&A2s[qs * AW + h * A_HEAD + lo * A_ROW + 32 * u + 8 * g + 4];
      __builtin_amdgcn_s_setprio(1);
      oacc[qs][0] = __builtin_amdgcn_mfma_f32_16x16x32_bf16(av.f8, vf0, oacc[qs][0], 0, 0, 0);
      oacc[qs][1] = __builtin_amdgcn_mfma_f32_16x16x32_bf16(av.f8, vf1, oacc[qs][1], 0, 0, 0);
      __builtin_amdgcn_s_setprio(0);
    }
    __syncthreads();
  }

  // ---- cross-u reduction via A2s scratch, write o_part [split][be][n][c] bf16 ----
  float* scr = (float*)A2s;
  if (u == 1) {
#pragma unroll
    for (int qs = 0; qs < 2; ++qs) {
      float4 f0; f0.x = oacc[qs][0][0]; f0.y = oacc[qs][0][1]; f0.z = oacc[qs][0][2]; f0.w = oacc[qs][0][3];
      float4 f1; f1.x = oacc[qs][1][0]; f1.y = oacc[qs][1][1]; f1.z = oacc[qs][1][2]; f1.w = oacc[qs][1][3];
      *(float4*)&scr[((qs * 4 + h) * 64 + lane) * 8] = f0;
      *(float4*)&scr[((qs * 4 + h) * 64 + lane) * 8 + 4] = f1;
    }
  }
  __syncthreads();
  if (u == 0) {
#pragma unroll
    for (int qs = 0; qs < 2; ++qs) {
      const float4 f0 = *(const float4*)&scr[((qs * 4 + h) * 64 + lane) * 8];
      const float4 f1 = *(const float4*)&scr[((qs * 4 + h) * 64 + lane) * 8 + 4];
      const float fa[4] = {f0.x, f0.y, f0.z, f0.w};
      const float fb[4] = {f1.x, f1.y, f1.z, f1.w};
#pragma unroll
      for (int r = 0; r < 4; r++) {
        const size_t rowoff = ((size_t)(split * 8 + be) * NAa + n0 + 16 * qs + 4 * g + r) * CC;
        o_part[rowoff + h * HD + lo] = f2bf(oacc[qs][0][r] + fa[r]);
        o_part[rowoff + h * HD + 16 + lo] = f2bf(oacc[qs][1][r] + fb[r]);
      }
    }
  }
}

// ---- K3: out as MFMA GEMM + SiLU-gate + residual ----
__global__ __launch_bounds__(256) void out_kernel(
    const unsigned short* __restrict__ o_part, const unsigned short* __restrict__ wob,
    const float* __restrict__ t_out, const float* __restrict__ x,
    float* __restrict__ out) {
  const int tid = threadIdx.x;
  const int w = tid >> 6, lane = tid & 63, lo = lane & 15, g = lane >> 4;
  const int blk = blockIdx.x;
  const int b = blk / 400, pt = blk - b * 400;
  const int ng0 = pt * 16;
  const int a = ng0 / NAa, na0 = ng0 - a * NAa;
  const int be = b * 4 + a;
  const size_t orow0 = ((size_t)(0 * 8 + be) * NAa + na0 + lo) * CC;
  const size_t orow1 = ((size_t)(1 * 8 + be) * NAa + na0 + lo) * CC;
  bfrag8 bf0[4], bf1[4];
#pragma unroll
  for (int kk = 0; kk < 4; kk++) {
    bf0[kk] = *(const bfrag8*)&o_part[orow0 + kk * 32 + g * 8];
    bf1[kk] = *(const bfrag8*)&o_part[orow1 + kk * 32 + g * 8];
  }
#pragma unroll
  for (int mt2 = 0; mt2 < 2; mt2++) {
    const int rowbase = (w * 2 + mt2) * 16;
    ffrag4 d = {0.f, 0.f, 0.f, 0.f};
#pragma unroll
    for (int kk = 0; kk < 4; kk++) {
      bfrag8 af = *(const bfrag8*)&wob[(size_t)(rowbase + lo) * CC + kk * 32 + g * 8];
      d = __builtin_amdgcn_mfma_f32_16x16x32_bf16(af, bf0[kk], d, 0, 0, 0);
      d = __builtin_amdgcn_mfma_f32_16x16x32_bf16(af, bf1[kk], d, 0, 0, 0);
    }
    const int ch0 = rowbase + 4 * g;
    const uint2 q0 = *(const uint2*)&o_part[orow0 + ch0];
    const uint2 q1 = *(const uint2*)&o_part[orow1 + ch0];
    float ov[4] = {bfl(q0.x) + bfl(q1.x), bfh(q0.x) + bfh(q1.x),
                   bfl(q0.y) + bfl(q1.y), bfh(q0.y) + bfh(q1.y)};
#pragma unroll
    for (int r = 0; r < 4; r++) {
      const size_t xi = ((size_t)b * CC + ch0 + r) * NN + ng0 + lo;
      float y = d[r] + t_out[ch0 + r];
      out[xi] = ov[r] * sigmoid_fast(y) + x[xi];
    }
  }
}

extern "C" void kernel_launch(void* const* d_in, const int* in_sizes, int n_in,
                              void* d_out, int out_size, void* d_ws, size_t ws_size,
                              hipStream_t stream) {
  const float* x    = (const float*)d_in[0];
  const float* w_qk = (const float*)d_in[1];
  const float* s_qk = (const float*)d_in[2];
  const float* t_qk = (const float*)d_in[3];
  const float* w_in = (const float*)d_in[4];
  const float* s_in = (const float*)d_in[5];
  const float* t_in = (const float*)d_in[6];
  const float* w_out = (const float*)d_in[7];
  const float* s_out = (const float*)d_in[8];
  const float* t_out = (const float*)d_in[9];
  const float* w_fg = (const float*)d_in[10];
  const float* s_fg = (const float*)d_in[11];
  const float* t_fg = (const float*)d_in[12];

  char* wsb = (char*)d_ws;
  unsigned short* o_part = (unsigned short*)wsb;               // 6,553,600 B  [split][be][n][c] bf16
  unsigned short* vb_raw = (unsigned short*)(wsb + 6553600);   // 3,276,864 B
  unsigned short* vbp = vb_raw + 2;
  unsigned short* qt = (unsigned short*)(wsb + 9830464);       // 3,276,800 B
  unsigned short* kt = (unsigned short*)(wsb + 13107264);      // 3,276,800 B
  unsigned short* wqkb = (unsigned short*)(wsb + 19660864);    //    98,304 B
  unsigned short* wob = (unsigned short*)(wsb + 19759168);     //    32,768 B
  float* pstats = (float*)(wsb + 19791936);                    // 1,638,400 B
  float* out = (float*)d_out;

  prep_kernel<<<10, 256, 0, stream>>>(w_qk, s_qk, w_in, s_in, w_out, s_out, wqkb, wob);
  qkv_kernel<<<800, 256, 0, stream>>>(x, wqkb, t_qk, t_in, qt, kt, vbp);
  stats_kernel<<<800, 256, 0, stream>>>(qt, kt, pstats);
  apply_kernel<<<800, 512, 0, stream>>>(qt, kt, vbp, pstats, w_fg, s_fg, t_fg, o_part);
  out_kernel<<<800, 256, 0, stream>>>(o_part, wob, t_out, x, out);
}

// Round 7
// 122.200 us; speedup vs baseline: 1.9073x; 1.0545x over previous
//
#include <hip/hip_runtime.h>
#include <hip/hip_bf16.h>
#include <cstdint>

#define CC 128
#define NN 6400
#define NAa 1600
#define HEADS 4
#define HD 32
#define NB 32
#define MT 64

#define P_ROW 68
#define P_HEAD 1096   // 16*68+8 pad
#define A_ROW 76
#define A_HEAD 1224   // 16*76+8 pad
#define PW (HEADS * P_HEAD)   // 4384 elems per q-subtile
#define AW (HEADS * A_HEAD)   // 4896 elems per q-subtile
// halo buffer: [parity][qs][h][lo][4] bf16
#define HB_IDX(par, qs, hh, lo) (((((par)*2 + (qs))*4 + (hh))*16 + (lo)) * 4)
#define XROW 136              // qkv LDS x-tile row stride (16B-aligned: 272 B)

typedef __attribute__((ext_vector_type(8))) short bfrag8;
typedef __attribute__((ext_vector_type(4))) float ffrag4;
typedef union { uint2 u2[2]; bfrag8 f8; } cvt16;

#define LOG2E 1.4426950408889634f
#define QSCL (0.17677669529663687f * 1.4426950408889634f)

__device__ __forceinline__ float sigmoid_fast(float y) {
  return __builtin_amdgcn_rcpf(1.0f + __builtin_amdgcn_exp2f(-LOG2E * y));
}
__device__ __forceinline__ unsigned short f2bf(float f) {
  unsigned u = __float_as_uint(f);
  return (unsigned short)((u + 0x7FFFu + ((u >> 16) & 1u)) >> 16);
}
// packed 2xf32 -> 2xbf16 (RNE) — should emit v_cvt_pk_bf16_f32
__device__ __forceinline__ unsigned pk2(float a, float b) {
  float2 f2; f2.x = a; f2.y = b;
  __hip_bfloat162 h = __float22bfloat162_rn(f2);
  union { __hip_bfloat162 h2; unsigned u; } cv; cv.h2 = h;
  return cv.u;
}
__device__ __forceinline__ float bfl(unsigned u) { return __uint_as_float(u << 16); }
__device__ __forceinline__ float bfh(unsigned u) { return __uint_as_float(u & 0xFFFF0000u); }

// ---- K0: prep — weights->bf16 with scales folded (x-transpose fused into qkv) ----
__global__ __launch_bounds__(256) void prep_kernel(
    const float* __restrict__ w_qk, const float* __restrict__ s_qk,
    const float* __restrict__ w_in, const float* __restrict__ s_in,
    const float* __restrict__ w_out, const float* __restrict__ s_out,
    unsigned short* __restrict__ wqkb, unsigned short* __restrict__ wob) {
  const int blk = blockIdx.x, tid = threadIdx.x;
  if (blk < 8) {
    const int r0 = blk * 48;
    for (int i = tid; i < 6144; i += 256) {
      int r = r0 + (i >> 7), c = i & 127;
      float wv, sv;
      if (r < 2 * CC) { wv = w_qk[r * CC + c]; sv = s_qk[r] * (r < CC ? QSCL : 1.0f); }
      else           { wv = w_in[(r - 2 * CC) * CC + c]; sv = s_in[r - 2 * CC]; }
      wqkb[r * CC + c] = f2bf(wv * sv);
    }
  } else {
    const int r0 = (blk - 8) * 64;
    for (int i = tid; i < 8192; i += 256) {
      int r = r0 + (i >> 7), c = i & 127;
      wob[r * CC + c] = f2bf(w_out[r * CC + c] * s_out[r]);
    }
  }
}

// ---- K1: qkv as MFMA GEMM (384 x 6400 x K=128), x transposed in-block via LDS ----
__global__ __launch_bounds__(256) void qkv_kernel(
    const float* __restrict__ x, const unsigned short* __restrict__ wqkb,
    const float* __restrict__ t_qk, const float* __restrict__ t_in,
    unsigned short* __restrict__ qt, unsigned short* __restrict__ kt,
    unsigned short* __restrict__ vb) {
  __shared__ __align__(16) unsigned short xb[16 * XROW];  // 4352 B
  const int tid = threadIdx.x;
  const int w = tid >> 6, lane = tid & 63, lo = lane & 15, g = lane >> 4;
  const int blk = blockIdx.x;
  const int b = blk / 400, pt = blk - b * 400;
  const int ng0 = pt * 16;
  const int a = ng0 / NAa, na0 = ng0 - a * NAa;
  const int be = b * 4 + a;
  // ---- stage: transpose x[b][c][ng0..ng0+15] f32 -> xb[n][c] bf16 ----
  {
    const int c = tid >> 1, half = tid & 1;
    const float* xr = &x[((size_t)(b * CC + c)) * NN + ng0 + 8 * half];
    const float4 f0 = *(const float4*)xr;
    const float4 f1 = *(const float4*)(xr + 4);
    unsigned short* dst = &xb[(8 * half) * XROW + c];
    dst[0 * XROW] = f2bf(f0.x); dst[1 * XROW] = f2bf(f0.y);
    dst[2 * XROW] = f2bf(f0.z); dst[3 * XROW] = f2bf(f0.w);
    dst[4 * XROW] = f2bf(f1.x); dst[5 * XROW] = f2bf(f1.y);
    dst[6 * XROW] = f2bf(f1.z); dst[7 * XROW] = f2bf(f1.w);
  }
  __syncthreads();
  bfrag8 bf[4];
#pragma unroll
  for (int kk = 0; kk < 4; kk++) bf[kk] = *(const bfrag8*)&xb[lo * XROW + kk * 32 + g * 8];
#pragma unroll
  for (int mt6 = 0; mt6 < 6; mt6++) {
    const int rowbase = (w * 6 + mt6) * 16;
    ffrag4 d = {0.f, 0.f, 0.f, 0.f};
#pragma unroll
    for (int kk = 0; kk < 4; kk++) {
      bfrag8 af = *(const bfrag8*)&wqkb[(size_t)(rowbase + lo) * CC + kk * 32 + g * 8];
      d = __builtin_amdgcn_mfma_f32_16x16x32_bf16(af, bf[kk], d, 0, 0, 0);
    }
    const int r0c = rowbase + 4 * g;
    if (r0c < CC) {
      const int h = r0c >> 5, d0 = r0c & 31;
      uint2 pk;
      pk.x = pk2(d[0] + t_qk[r0c] * QSCL, d[1] + t_qk[r0c + 1] * QSCL);
      pk.y = pk2(d[2] + t_qk[r0c + 2] * QSCL, d[3] + t_qk[r0c + 3] * QSCL);
      *(uint2*)&qt[((size_t)(be * HEADS + h) * NAa + na0 + lo) * HD + d0] = pk;
    } else if (r0c < 2 * CC) {
      const int ch = r0c - CC, h = ch >> 5, d0 = ch & 31;
      uint2 pk;
      pk.x = pk2(d[0] + t_qk[r0c], d[1] + t_qk[r0c + 1]);
      pk.y = pk2(d[2] + t_qk[r0c + 2], d[3] + t_qk[r0c + 3]);
      *(uint2*)&kt[((size_t)(be * HEADS + h) * NAa + na0 + lo) * HD + d0] = pk;
    } else {
      const int ch0 = r0c - 2 * CC;
      const uint2 xv = *(const uint2*)&xb[lo * XROW + ch0];
      float xr[4] = {bfl(xv.x), bfh(xv.x), bfl(xv.y), bfh(xv.y)};
#pragma unroll
      for (int r = 0; r < 4; r++) {
        float y = d[r] + t_in[ch0 + r];
        vb[((size_t)be * CC + ch0 + r) * NAa + na0 + lo] = f2bf(sigmoid_fast(y) * xr[r]);
      }
    }
  }
}

// ---- K2a: partial softmax denominators (M0 = 0, q pre-scaled), 32 q/block ----
__global__ __launch_bounds__(256) void stats_kernel(
    const unsigned short* __restrict__ qt, const unsigned short* __restrict__ kt,
    float* __restrict__ pstats) {
  int tid = threadIdx.x;
  int h = tid >> 6, lane = tid & 63, lo = lane & 15, g = lane >> 4;
  int bid = blockIdx.x;
  int be = bid & 7;
  int rest = bid >> 3;
  int n0 = (rest % 50) * 32;
  int split = rest / 50;
  int ts0 = split ? 12 : 0, ts1 = split ? 25 : 12;

  const unsigned short* qtb = qt + (size_t)(be * HEADS + h) * NAa * HD;
  const unsigned short* ktb = kt + (size_t)(be * HEADS + h) * NAa * HD;

  bfrag8 qf0 = *(const bfrag8*)(qtb + (size_t)(n0 + lo) * HD + g * 8);
  bfrag8 qf1 = *(const bfrag8*)(qtb + (size_t)(n0 + 16 + lo) * HD + g * 8);
  float sm0[4] = {0.f, 0.f, 0.f, 0.f};
  float sm1[4] = {0.f, 0.f, 0.f, 0.f};
  for (int t = ts0; t < ts1; t++) {
    int m0 = t * MT;
#pragma unroll
    for (int sb = 0; sb < 4; sb++) {
      bfrag8 kf = *(const bfrag8*)(ktb + (size_t)(m0 + sb * 16 + lo) * HD + g * 8);
      ffrag4 z = {0.f, 0.f, 0.f, 0.f};
      ffrag4 c0 = __builtin_amdgcn_mfma_f32_16x16x32_bf16(qf0, kf, z, 0, 0, 0);
      ffrag4 c1 = __builtin_amdgcn_mfma_f32_16x16x32_bf16(qf1, kf, z, 0, 0, 0);
#pragma unroll
      for (int r = 0; r < 4; r++) {
        sm0[r] += __builtin_amdgcn_exp2f(c0[r]);
        sm1[r] += __builtin_amdgcn_exp2f(c1[r]);
      }
    }
  }
#pragma unroll
  for (int r = 0; r < 4; r++) {
#pragma unroll
    for (int off = 1; off <= 8; off <<= 1) {
      sm0[r] += __shfl_xor(sm0[r], off);
      sm1[r] += __shfl_xor(sm1[r], off);
    }
  }
  if (lo == 0) {
    float4 s4; s4.x = sm0[0]; s4.y = sm0[1]; s4.z = sm0[2]; s4.w = sm0[3];
    *(float4*)&pstats[((size_t)(split * 8 + be) * HEADS + h) * NAa + n0 + 4 * g] = s4;
    float4 s5; s5.x = sm1[0]; s5.y = sm1[1]; s5.z = sm1[2]; s5.w = sm1[3];
    *(float4*)&pstats[((size_t)(split * 8 + be) * HEADS + h) * NAa + n0 + 16 + 4 * g] = s5;
  }
}

// ---- K2b: apply — NB=32 tile, single-buffered P + parity halo Hb, 3-WAY key
//      split (tiles [0,9)/[9,17)/[17,26), grid 1200): sustains 4 blocks/CU
//      (LDS 39.4 KB cap) with phase-STAGGERED block starts -> breaks the
//      barrier convoy R6's setprio null confirmed. No setprio (it regressed).
__global__ __launch_bounds__(512) void apply_kernel(
    const unsigned short* __restrict__ qt, const unsigned short* __restrict__ kt,
    const unsigned short* __restrict__ vb, const float* __restrict__ pstats,
    const float* __restrict__ w_fg, const float* __restrict__ s_fg,
    const float* __restrict__ t_fg, unsigned short* __restrict__ o_part) {
  __shared__ __align__(16) unsigned short Ps[2 * PW];   // 17536 B
  __shared__ __align__(16) unsigned short A2s[2 * AW];  // 19584 B
  __shared__ __align__(16) unsigned short Hb[1024];     //  2048 B halo [par][qs][h][lo][4]
  const int tid = threadIdx.x;
  const int w = tid >> 6, lane = tid & 63, lo = lane & 15, g = lane >> 4;
  const int h = w >> 1, u = w & 1;
  const int bid = blockIdx.x;
  const int be = bid & 7;
  const int rest = bid >> 3;
  const int n0 = (rest % 50) * NB;
  const int split = rest / 50;                         // 0..2
  const int ts0 = (split == 0) ? 0 : (split == 1 ? 9 : 17);
  const int tend = (split == 0) ? 9 : (split == 1 ? 17 : 26);  // t=25 virtual tail
  const int p0 = ts0 & 1;

  const unsigned short* qtb = qt + (size_t)(be * HEADS + h) * NAa * HD;
  const unsigned short* ktb = kt + (size_t)(be * HEADS + h) * NAa * HD;
  const unsigned short* vhb = vb + (size_t)(be * CC + h * HD) * NAa;

  bfrag8 qf[2];
#pragma unroll
  for (int qs = 0; qs < 2; ++qs)
    qf[qs] = *(const bfrag8*)(qtb + (size_t)(n0 + 16 * qs + lo) * HD + g * 8);

  // conv-weight A-fragment (constant): row=lo=(ho*4+s), k=g*8+j
  bfrag8 wfrag;
  {
    const int ho = lo >> 2, s = lo & 3;
#pragma unroll
    for (int j = 0; j < 8; j++) {
      const int tp = j - s;
      float wv = (tp >= 0 && tp < 5) ? w_fg[(ho * HEADS + g) * 5 + tp] : 0.0f;
      wfrag[j] = (short)f2bf(wv);
    }
  }
  const float sfv = s_fg[g], tfv = t_fg[g];

  // -log2(denominator) per q-subtile, folded into QK's MFMA accumulator
  float linv[2];
#pragma unroll
  for (int qs = 0; qs < 2; ++qs) {
    const float den = pstats[((size_t)(0 + be) * HEADS + h) * NAa + n0 + 16 * qs + lo] +
                      pstats[((size_t)(8 + be) * HEADS + h) * NAa + n0 + 16 * qs + lo];
    linv[qs] = -__log2f(den);
  }

  ffrag4 oacc[2][2];
#pragma unroll
  for (int qs = 0; qs < 2; ++qs) {
    ffrag4 z = {0.f, 0.f, 0.f, 0.f};
    oacc[qs][0] = z; oacc[qs][1] = z;
  }

  // ---- prologue: Hb[p0] = halo for conv(ts0) ----
  if (split == 0) {
    if (u == 0 && g == 0) {
      uint2 zz; zz.x = 0; zz.y = 0;
#pragma unroll
      for (int qs = 0; qs < 2; ++qs)
        *(uint2*)&Hb[HB_IDX(p0, qs, h, lo)] = zz;
    }
  } else if (u == 0) {
    // halo keys ts0*64-4..-1 from K rows ts0*64-16..-1 (g==3 lanes hold them)
    bfrag8 kf = *(const bfrag8*)(ktb + (size_t)(ts0 * MT - 16 + lo) * HD + g * 8);
#pragma unroll
    for (int qs = 0; qs < 2; ++qs) {
      ffrag4 cin = {linv[qs], linv[qs], linv[qs], linv[qs]};
      ffrag4 c = __builtin_amdgcn_mfma_f32_16x16x32_bf16(kf, qf[qs], cin, 0, 0, 0);
      if (g == 3) {
        uint2 pk;
        pk.x = pk2(__builtin_amdgcn_exp2f(c[0]), __builtin_amdgcn_exp2f(c[1]));
        pk.y = pk2(__builtin_amdgcn_exp2f(c[2]), __builtin_amdgcn_exp2f(c[3]));
        *(uint2*)&Hb[HB_IDX(p0, qs, h, lo)] = pk;
      }
    }
  }
  // ---- prologue: QK(ts0) -> Ps; sb==3/g==3 lanes also feed Hb[p0^1] ----
  {
    const int m0 = ts0 * MT;
#pragma unroll
    for (int sbi = 0; sbi < 2; sbi++) {
      const int sb = 2 * u + sbi;
      bfrag8 kf = *(const bfrag8*)(ktb + (size_t)(m0 + sb * 16 + lo) * HD + g * 8);
#pragma unroll
      for (int qs = 0; qs < 2; ++qs) {
        ffrag4 cin = {linv[qs], linv[qs], linv[qs], linv[qs]};
        ffrag4 c = __builtin_amdgcn_mfma_f32_16x16x32_bf16(kf, qf[qs], cin, 0, 0, 0);
        uint2 pk;
        pk.x = pk2(__builtin_amdgcn_exp2f(c[0]), __builtin_amdgcn_exp2f(c[1]));
        pk.y = pk2(__builtin_amdgcn_exp2f(c[2]), __builtin_amdgcn_exp2f(c[3]));
        *(uint2*)&Ps[qs * PW + h * P_HEAD + lo * P_ROW + 16 * sb + 4 * g] = pk;
        if (sb == 3 && g == 3)
          *(uint2*)&Hb[HB_IDX(p0 ^ 1, qs, h, lo)] = pk;
      }
    }
  }
  __syncthreads();

  for (int t = ts0; t < tend; t++) {
    const int m0 = t * MT;
    const int par = t & 1;
    // early V loads (k-half u) for PV(t) — shared across q-subtiles
    const bfrag8 vf0 = *(const bfrag8*)(vhb + (size_t)lo * NAa + (m0 - 2 + 32 * u + 8 * g));
    const bfrag8 vf1 = *(const bfrag8*)(vhb + (size_t)(16 + lo) * NAa + (m0 - 2 + 32 * u + 8 * g));
    const bool doqk = (t + 1 < tend);
    const bool realqk = doqk && (t + 1 < 25);
    bfrag8 kf0, kf1;
    if (realqk) {
      const int m1 = (t + 1) * MT;
      kf0 = *(const bfrag8*)(ktb + (size_t)(m1 + (2 * u) * 16 + lo) * HD + g * 8);
      kf1 = *(const bfrag8*)(ktb + (size_t)(m1 + (2 * u + 1) * 16 + lo) * HD + g * 8);
    }
    // ---- phase 1: conv(t) reads Ps/Hb -> writes A2s ----
    const bool edge = (t == 0) || (t == 25);
#pragma unroll
    for (int qs = 0; qs < 2; ++qs) {
#pragma unroll
      for (int ii = 0; ii < 2; ii++) {
        const int i = 2 * w + ii;
        cvt16 bb;
        if (i == 0)
          bb.u2[0] = *(const uint2*)&Hb[HB_IDX(par, qs, g, lo)];
        else
          bb.u2[0] = *(const uint2*)&Ps[qs * PW + g * P_HEAD + lo * P_ROW + 4 * i - 4];
        bb.u2[1] = *(const uint2*)&Ps[qs * PW + g * P_HEAD + lo * P_ROW + 4 * i];
        ffrag4 z = {0.f, 0.f, 0.f, 0.f};
        ffrag4 d = __builtin_amdgcn_mfma_f32_16x16x32_bf16(wfrag, bb.f8, z, 0, 0, 0);
        float a2v[4];
        if (edge) {
#pragma unroll
          for (int r = 0; r < 4; r++) {
            const int mp = m0 - 2 + 4 * i + r;
            float y = d[r] * sfv + tfv;
            float v = y * sigmoid_fast(y);
            a2v[r] = (mp >= 0 && mp < NAa) ? v : 0.0f;
          }
        } else {
#pragma unroll
          for (int r = 0; r < 4; r++) {
            float y = d[r] * sfv + tfv;
            a2v[r] = y * sigmoid_fast(y);
          }
        }
        uint2 pk;
        pk.x = pk2(a2v[0], a2v[1]);
        pk.y = pk2(a2v[2], a2v[3]);
        *(uint2*)&A2s[qs * AW + g * A_HEAD + lo * A_ROW + 4 * i] = pk;
      }
    }
    __syncthreads();
    // ---- phase 2: QK(t+1) -> Ps/Hb, then PV(t) reads A2s ----
    if (doqk) {
      if (realqk) {
#pragma unroll
        for (int qs = 0; qs < 2; ++qs) {
          ffrag4 cin = {linv[qs], linv[qs], linv[qs], linv[qs]};
          ffrag4 c0 = __builtin_amdgcn_mfma_f32_16x16x32_bf16(kf0, qf[qs], cin, 0, 0, 0);
          ffrag4 c1 = __builtin_amdgcn_mfma_f32_16x16x32_bf16(kf1, qf[qs], cin, 0, 0, 0);
          uint2 pk;
          pk.x = pk2(__builtin_amdgcn_exp2f(c0[0]), __builtin_amdgcn_exp2f(c0[1]));
          pk.y = pk2(__builtin_amdgcn_exp2f(c0[2]), __builtin_amdgcn_exp2f(c0[3]));
          *(uint2*)&Ps[qs * PW + h * P_HEAD + lo * P_ROW + 16 * (2 * u) + 4 * g] = pk;
          uint2 pk1;
          pk1.x = pk2(__builtin_amdgcn_exp2f(c1[0]), __builtin_amdgcn_exp2f(c1[1]));
          pk1.y = pk2(__builtin_amdgcn_exp2f(c1[2]), __builtin_amdgcn_exp2f(c1[3]));
          *(uint2*)&Ps[qs * PW + h * P_HEAD + lo * P_ROW + 16 * (2 * u + 1) + 4 * g] = pk1;
          if (u == 1 && g == 3)
            *(uint2*)&Hb[HB_IDX(par, qs, h, lo)] = pk1;   // halo for conv(t+2)
        }
      } else {
        uint2 zz; zz.x = 0; zz.y = 0;
#pragma unroll
        for (int qs = 0; qs < 2; ++qs) {
          *(uint2*)&Ps[qs * PW + h * P_HEAD + lo * P_ROW + 16 * (2 * u) + 4 * g] = zz;
          *(uint2*)&Ps[qs * PW + h * P_HEAD + lo * P_ROW + 16 * (2 * u + 1) + 4 * g] = zz;
        }
      }
    }
    // PV(t): head h, k-half u, both qsubs (V frags shared)
#pragma unroll
    for (int qs = 0; qs < 2; ++qs) {
      cvt16 av;
      av.u2[0] = *(const uint2*)&A2s[qs * AW + h * A_HEAD + lo * A_ROW + 32 * u + 8 * g];
      av.u2[1] = *(const uint2*)&A2s[qs * AW + h * A_HEAD + lo * A_ROW + 32 * u + 8 * g + 4];
      oacc[qs][0] = __builtin_amdgcn_mfma_f32_16x16x32_bf16(av.f8, vf0, oacc[qs][0], 0, 0, 0);
      oacc[qs][1] = __builtin_amdgcn_mfma_f32_16x16x32_bf16(av.f8, vf1, oacc[qs][1], 0, 0, 0);
    }
    __syncthreads();
  }

  // ---- cross-u reduction via A2s scratch, write o_part [split][be][n][c] bf16 ----
  float* scr = (float*)A2s;
  if (u == 1) {
#pragma unroll
    for (int qs = 0; qs < 2; ++qs) {
      float4 f0; f0.x = oacc[qs][0][0]; f0.y = oacc[qs][0][1]; f0.z = oacc[qs][0][2]; f0.w = oacc[qs][0][3];
      float4 f1; f1.x = oacc[qs][1][0]; f1.y = oacc[qs][1][1]; f1.z = oacc[qs][1][2]; f1.w = oacc[qs][1][3];
      *(float4*)&scr[((qs * 4 + h) * 64 + lane) * 8] = f0;
      *(float4*)&scr[((qs * 4 + h) * 64 + lane) * 8 + 4] = f1;
    }
  }
  __syncthreads();
  if (u == 0) {
#pragma unroll
    for (int qs = 0; qs < 2; ++qs) {
      const float4 f0 = *(const float4*)&scr[((qs * 4 + h) * 64 + lane) * 8];
      const float4 f1 = *(const float4*)&scr[((qs * 4 + h) * 64 + lane) * 8 + 4];
      const float fa[4] = {f0.x, f0.y, f0.z, f0.w};
      const float fb[4] = {f1.x, f1.y, f1.z, f1.w};
#pragma unroll
      for (int r = 0; r < 4; r++) {
        const size_t rowoff = ((size_t)(split * 8 + be) * NAa + n0 + 16 * qs + 4 * g + r) * CC;
        o_part[rowoff + h * HD + lo] = f2bf(oacc[qs][0][r] + fa[r]);
        o_part[rowoff + h * HD + 16 + lo] = f2bf(oacc[qs][1][r] + fb[r]);
      }
    }
  }
}

// ---- K3: out as MFMA GEMM + SiLU-gate + residual (sums 3 o_part splits) ----
__global__ __launch_bounds__(256) void out_kernel(
    const unsigned short* __restrict__ o_part, const unsigned short* __restrict__ wob,
    const float* __restrict__ t_out, const float* __restrict__ x,
    float* __restrict__ out) {
  const int tid = threadIdx.x;
  const int w = tid >> 6, lane = tid & 63, lo = lane & 15, g = lane >> 4;
  const int blk = blockIdx.x;
  const int b = blk / 400, pt = blk - b * 400;
  const int ng0 = pt * 16;
  const int a = ng0 / NAa, na0 = ng0 - a * NAa;
  const int be = b * 4 + a;
  const size_t orow0 = ((size_t)(0 * 8 + be) * NAa + na0 + lo) * CC;
  const size_t orow1 = ((size_t)(1 * 8 + be) * NAa + na0 + lo) * CC;
  const size_t orow2 = ((size_t)(2 * 8 + be) * NAa + na0 + lo) * CC;
  bfrag8 bf0[4], bf1[4], bf2[4];
#pragma unroll
  for (int kk = 0; kk < 4; kk++) {
    bf0[kk] = *(const bfrag8*)&o_part[orow0 + kk * 32 + g * 8];
    bf1[kk] = *(const bfrag8*)&o_part[orow1 + kk * 32 + g * 8];
    bf2[kk] = *(const bfrag8*)&o_part[orow2 + kk * 32 + g * 8];
  }
#pragma unroll
  for (int mt2 = 0; mt2 < 2; mt2++) {
    const int rowbase = (w * 2 + mt2) * 16;
    ffrag4 d = {0.f, 0.f, 0.f, 0.f};
#pragma unroll
    for (int kk = 0; kk < 4; kk++) {
      bfrag8 af = *(const bfrag8*)&wob[(size_t)(rowbase + lo) * CC + kk * 32 + g * 8];
      d = __builtin_amdgcn_mfma_f32_16x16x32_bf16(af, bf0[kk], d, 0, 0, 0);
      d = __builtin_amdgcn_mfma_f32_16x16x32_bf16(af, bf1[kk], d, 0, 0, 0);
      d = __builtin_amdgcn_mfma_f32_16x16x32_bf16(af, bf2[kk], d, 0, 0, 0);
    }
    const int ch0 = rowbase + 4 * g;
    const uint2 q0 = *(const uint2*)&o_part[orow0 + ch0];
    const uint2 q1 = *(const uint2*)&o_part[orow1 + ch0];
    const uint2 q2 = *(const uint2*)&o_part[orow2 + ch0];
    float ov[4] = {bfl(q0.x) + bfl(q1.x) + bfl(q2.x), bfh(q0.x) + bfh(q1.x) + bfh(q2.x),
                   bfl(q0.y) + bfl(q1.y) + bfl(q2.y), bfh(q0.y) + bfh(q1.y) + bfh(q2.y)};
#pragma unroll
    for (int r = 0; r < 4; r++) {
      const size_t xi = ((size_t)b * CC + ch0 + r) * NN + ng0 + lo;
      float y = d[r] + t_out[ch0 + r];
      out[xi] = ov[r] * sigmoid_fast(y) + x[xi];
    }
  }
}

extern "C" void kernel_launch(void* const* d_in, const int* in_sizes, int n_in,
                              void* d_out, int out_size, void* d_ws, size_t ws_size,
                              hipStream_t stream) {
  const float* x    = (const float*)d_in[0];
  const float* w_qk = (const float*)d_in[1];
  const float* s_qk = (const float*)d_in[2];
  const float* t_qk = (const float*)d_in[3];
  const float* w_in = (const float*)d_in[4];
  const float* s_in = (const float*)d_in[5];
  const float* t_in = (const float*)d_in[6];
  const float* w_out = (const float*)d_in[7];
  const float* s_out = (const float*)d_in[8];
  const float* t_out = (const float*)d_in[9];
  const float* w_fg = (const float*)d_in[10];
  const float* s_fg = (const float*)d_in[11];
  const float* t_fg = (const float*)d_in[12];

  char* wsb = (char*)d_ws;
  unsigned short* o_part = (unsigned short*)wsb;               // 9,830,400 B  [3 split][be][n][c] bf16
  unsigned short* vb_raw = (unsigned short*)(wsb + 9830400);   // 3,276,864 B
  unsigned short* vbp = vb_raw + 2;
  unsigned short* qt = (unsigned short*)(wsb + 13107264);      // 3,276,800 B
  unsigned short* kt = (unsigned short*)(wsb + 16384064);      // 3,276,800 B
  unsigned short* wqkb = (unsigned short*)(wsb + 19660864);    //    98,304 B
  unsigned short* wob = (unsigned short*)(wsb + 19759168);     //    32,768 B
  float* pstats = (float*)(wsb + 19791936);                    // 1,638,400 B -> total 21,430,336 B (same as before)
  float* out = (float*)d_out;

  prep_kernel<<<10, 256, 0, stream>>>(w_qk, s_qk, w_in, s_in, w_out, s_out, wqkb, wob);
  qkv_kernel<<<800, 256, 0, stream>>>(x, wqkb, t_qk, t_in, qt, kt, vbp);
  stats_kernel<<<800, 256, 0, stream>>>(qt, kt, pstats);
  apply_kernel<<<1200, 512, 0, stream>>>(qt, kt, vbp, pstats, w_fg, s_fg, t_fg, o_part);
  out_kernel<<<800, 256, 0, stream>>>(o_part, wob, t_out, x, out);
}